// Round 12
// baseline (534.805 us; speedup 1.0000x reference)
//
#include <hip/hip_runtime.h>
#include <hip/hip_bf16.h>
#include <math.h>
#include <stdio.h>

#define HEADS 10
#define CH 78
#define F 780          // HEADS*CH
#define NGRAPH 512
#define NEG 0.2f
#define KPAD 832       // GCN GEMM K: 780 padded to mult of 64
#define NPAD 896       // GCN GEMM N: 780 padded to mult of 128
#define K1 128         // transform GEMM K: 78 padded to mult of 64
#define N1 1560        // transform GEMM N: 780 (xl) + 780 (xr)
#define N1PAD 1664     // 1560 padded to mult of 128
#define K2PAD 1600     // FC1 K: 1560 padded to mult of 64
#define N2PAD 1536     // FC1 N: 1500 padded to mult of 128 (also FC2 K with zero pad)
#define ECAP 1024      // LDS edge-list chunk

typedef __attribute__((ext_vector_type(8))) short short8;
typedef __attribute__((ext_vector_type(4))) float f32x4;

#if __has_builtin(__builtin_amdgcn_exp2f)
#define EXP2F(x) __builtin_amdgcn_exp2f(x)
#else
#define EXP2F(x) exp2f(x)
#endif

__device__ inline void bf2unpack(unsigned int u, float& lo, float& hi) {
  union { unsigned int ui; float f; } a, b;
  a.ui = u << 16;
  b.ui = u & 0xffff0000u;
  lo = a.f; hi = b.f;
}

// ---------------- merged preprocessing: casts + counts init + out init ----------
__global__ __launch_bounds__(256) void prep_k(const float* __restrict__ x,
                                              const float* __restrict__ Wl,
                                              const float* __restrict__ Wr,
                                              const float* __restrict__ Wgcn,
                                              const float* __restrict__ Wfc1,
                                              const float* __restrict__ Wfc2,
                                              const float* __restrict__ bfc2,
                                              __hip_bfloat16* __restrict__ xb,
                                              __hip_bfloat16* __restrict__ Wlrb,
                                              __hip_bfloat16* __restrict__ Wtb,
                                              __hip_bfloat16* __restrict__ Wfc1b,
                                              __hip_bfloat16* __restrict__ Wfc2b,
                                              float* __restrict__ outinit,
                                              int* __restrict__ counts, int Nn) {
  int i = blockIdx.x * 256 + threadIdx.x;
  int s0 = Nn * K1;
  int s1 = s0 + N1PAD * K1;
  int s2 = s1 + NPAD * KPAD;
  int s3 = s2 + N2PAD * K2PAD;
  int s4 = s3 + 128 * N2PAD;
  int s5 = s4 + NGRAPH * 128;
  int s6 = s5 + Nn;
  if (i < s0) {
    int row = i / K1, k = i - row * K1;
    xb[i] = __float2bfloat16((k < 78) ? x[(size_t)row * 78 + k] : 0.f);
  } else if (i < s1) {
    int j = i - s0;
    int n = j / K1, k = j - n * K1;
    float v = 0.f;
    if (k < 78 && n < N1) v = (n < F) ? Wl[(size_t)k * F + n] : Wr[(size_t)k * F + (n - F)];
    Wlrb[j] = __float2bfloat16(v);
  } else if (i < s2) {
    int j = i - s1;
    int n = j / KPAD, k = j - n * KPAD;
    float v = (n < F && k < F) ? Wgcn[(size_t)k * F + n] : 0.f;
    Wtb[j] = __float2bfloat16(v);
  } else if (i < s3) {
    int j = i - s2;
    int n = j / K2PAD, k = j - n * K2PAD;
    float v = (n < 1500 && k < 1560) ? Wfc1[(size_t)k * 1500 + n] : 0.f;
    Wfc1b[j] = __float2bfloat16(v);
  } else if (i < s4) {
    int j = i - s3;
    int n = j / N2PAD, k = j - n * N2PAD;     // n: out col 0..127, k: 0..1535
    float v = (k < 1500) ? Wfc2[(size_t)k * 128 + n] : 0.f;
    Wfc2b[j] = __float2bfloat16(v);
  } else if (i < s5) {
    int j = i - s4;
    outinit[j] = bfc2[j & 127];
  } else if (i < s6) {
    counts[i - s5] = 1;   // self-loop
  }
}

// ---------------- bf16 MFMA GEMM core, BK=64 ----------------
__device__ inline void gl_lds16(const unsigned short* g, unsigned short* l) {
  __builtin_amdgcn_global_load_lds(
      (const __attribute__((address_space(1))) unsigned int*)g,
      (__attribute__((address_space(3))) unsigned int*)l, 16, 0, 0);
}

// A: [M][lda] bf16 row-major, Bt: [Ncols_pad][lda] bf16 (B transposed). K mult of 64.
// 128x128 tile, 4 waves x (4x4) mfma_f32_16x16x32_bf16.
#define MFMA_CORE64(A, Bt, lda, K)                                                \
  __shared__ unsigned short As[128 * 64];                                         \
  __shared__ unsigned short Bs[128 * 64];                                         \
  int tid = threadIdx.x;                                                          \
  int wave = tid >> 6, lane = tid & 63;                                           \
  int m0 = blockIdx.y * 128, n0 = blockIdx.x * 128;                               \
  int wr = (wave >> 1) * 64, wc = (wave & 1) * 64;                                \
  f32x4 acc[4][4];                                                                \
  _Pragma("unroll")                                                               \
  for (int i = 0; i < 4; ++i)                                                     \
    _Pragma("unroll")                                                             \
    for (int j = 0; j < 4; ++j) acc[i][j] = (f32x4){0.f, 0.f, 0.f, 0.f};          \
  int lrow = lane >> 3;                                                           \
  int lcol = (lane & 7) * 8;                                                      \
  const unsigned short* gA0 = A + (size_t)(m0 + wave * 32 + lrow) * lda + lcol;   \
  const unsigned short* gB0 = Bt + (size_t)(n0 + wave * 32 + lrow) * lda + lcol;  \
  unsigned short* lA = As + (wave * 32) * 64;                                     \
  unsigned short* lB = Bs + (wave * 32) * 64;                                     \
  int q8 = (lane >> 4) * 8;                                                       \
  int fr = lane & 15;                                                             \
  for (int k0 = 0; k0 < K; k0 += 64) {                                            \
    _Pragma("unroll")                                                             \
    for (int c = 0; c < 4; ++c) {                                                 \
      gl_lds16(gA0 + (size_t)(8 * c) * lda, lA + (8 * c) * 64);                   \
      gl_lds16(gB0 + (size_t)(8 * c) * lda, lB + (8 * c) * 64);                   \
    }                                                                             \
    gA0 += 64; gB0 += 64;                                                         \
    __syncthreads();                                                              \
    _Pragma("unroll")                                                             \
    for (int ks = 0; ks < 64; ks += 32) {                                         \
      short8 a[4], b[4];                                                          \
      _Pragma("unroll")                                                           \
      for (int i = 0; i < 4; ++i) a[i] = *(const short8*)&As[(wr + 16 * i + fr) * 64 + ks + q8]; \
      _Pragma("unroll")                                                           \
      for (int j = 0; j < 4; ++j) b[j] = *(const short8*)&Bs[(wc + 16 * j + fr) * 64 + ks + q8]; \
      _Pragma("unroll")                                                           \
      for (int i = 0; i < 4; ++i)                                                 \
        _Pragma("unroll")                                                         \
        for (int j = 0; j < 4; ++j)                                               \
          acc[i][j] = __builtin_amdgcn_mfma_f32_16x16x32_bf16(a[i], b[j], acc[i][j], 0, 0, 0); \
    }                                                                             \
    __syncthreads();                                                              \
  }                                                                               \
  int cq = (lane >> 4) * 4;

// variant 1: dual bf16 output (cols < F -> Cl stride F; cols >= F -> Cr stride F)
__global__ __launch_bounds__(256) void gemm_bf16_dual_k(const unsigned short* __restrict__ A,
                                                        const unsigned short* __restrict__ Bt,
                                                        __hip_bfloat16* __restrict__ Cl,
                                                        __hip_bfloat16* __restrict__ Cr,
                                                        int M, int Ncols, int K, int lda) {
  MFMA_CORE64(A, Bt, lda, K)
#pragma unroll
  for (int i = 0; i < 4; ++i) {
#pragma unroll
    for (int j = 0; j < 4; ++j) {
      int col = n0 + wc + 16 * j + fr;
      if (col >= Ncols) continue;
      int rowb = m0 + wr + 16 * i + cq;
#pragma unroll
      for (int r = 0; r < 4; ++r) {
        int row = rowb + r;
        if (row >= M) continue;
        float v = acc[i][j][r];
        if (col < F) Cl[(size_t)row * F + col] = __float2bfloat16(v);
        else         Cr[(size_t)row * F + (col - F)] = __float2bfloat16(v);
      }
    }
  }
}

// variant 2: bf16 output, row stride Ncols
__global__ __launch_bounds__(256) void gemm_bf16_obf_k(const unsigned short* __restrict__ A,
                                                       const unsigned short* __restrict__ Bt,
                                                       __hip_bfloat16* __restrict__ C,
                                                       int M, int Ncols, int K, int lda) {
  MFMA_CORE64(A, Bt, lda, K)
#pragma unroll
  for (int i = 0; i < 4; ++i) {
#pragma unroll
    for (int j = 0; j < 4; ++j) {
      int col = n0 + wc + 16 * j + fr;
      if (col >= Ncols) continue;
      int rowb = m0 + wr + 16 * i + cq;
#pragma unroll
      for (int r = 0; r < 4; ++r) {
        int row = rowb + r;
        if (row < M) C[(size_t)row * Ncols + col] = __float2bfloat16(acc[i][j][r]);
      }
    }
  }
}

// variant 3 (FC1): bias+relu epilogue, bf16 output stride N2PAD, zero pad cols >= Nreal
__global__ __launch_bounds__(256) void gemm_bf16_fc1_k(const unsigned short* __restrict__ A,
                                                       const unsigned short* __restrict__ Bt,
                                                       const float* __restrict__ bias,
                                                       __hip_bfloat16* __restrict__ C,
                                                       int M, int Nreal, int K, int lda) {
  MFMA_CORE64(A, Bt, lda, K)
#pragma unroll
  for (int i = 0; i < 4; ++i) {
#pragma unroll
    for (int j = 0; j < 4; ++j) {
      int col = n0 + wc + 16 * j + fr;
      int rowb = m0 + wr + 16 * i + cq;
#pragma unroll
      for (int r = 0; r < 4; ++r) {
        int row = rowb + r;
        if (row >= M) continue;
        float v = 0.f;
        if (col < Nreal) v = fmaxf(acc[i][j][r] + bias[col], 0.f);
        C[(size_t)row * N2PAD + col] = __float2bfloat16(v);
      }
    }
  }
}

// variant 4 (FC2): split-K over blockIdx.z, f32 atomicAdd into pre-initialized C [M x 128]
__global__ __launch_bounds__(256) void gemm_bf16_fc2_k(const unsigned short* __restrict__ A,
                                                       const unsigned short* __restrict__ Bt,
                                                       float* C, int M, int kchunk) {
  const unsigned short* A2 = A + (size_t)blockIdx.z * kchunk;
  const unsigned short* B2 = Bt + (size_t)blockIdx.z * kchunk;
  MFMA_CORE64(A2, B2, N2PAD, kchunk)
#pragma unroll
  for (int i = 0; i < 4; ++i) {
#pragma unroll
    for (int j = 0; j < 4; ++j) {
      int col = n0 + wc + 16 * j + fr;   // n0 == 0, col < 128
      int rowb = m0 + wr + 16 * i + cq;
#pragma unroll
      for (int r = 0; r < 4; ++r) {
        int row = rowb + r;
        if (row < M && col < 128) atomicAdd(&C[(size_t)row * 128 + col], acc[i][j][r]);
      }
    }
  }
}

// ---------------- CSR build (by dst, self-loop first per node) ----------------
__global__ void count_k(const int* __restrict__ dstv, int E, int* counts) {
  for (int e = blockIdx.x * blockDim.x + threadIdx.x; e < E; e += gridDim.x * blockDim.x)
    atomicAdd(&counts[dstv[e]], 1);
}
// scan + node init fused: row_start, self-loop slot, cursor, dinv
__global__ __launch_bounds__(256) void scan_k(const int* __restrict__ counts,
                                              int* __restrict__ row_start,
                                              int* __restrict__ cursor,
                                              int* __restrict__ csr_src,
                                              float* __restrict__ dinv, int Nn) {
  __shared__ int part[256];
  int t = threadIdx.x;
  int chunk = (Nn + 255) / 256;
  int b0 = t * chunk, b1 = min(b0 + chunk, Nn);
  int s = 0;
  for (int i = b0; i < b1; ++i) s += counts[i];
  part[t] = s;
  __syncthreads();
  // Hillis-Steele inclusive scan over 256 partials
  for (int off = 1; off < 256; off <<= 1) {
    int u = (t >= off) ? part[t - off] : 0;
    __syncthreads();
    part[t] += u;
    __syncthreads();
  }
  int run = part[t] - s;   // exclusive prefix for this thread's chunk
  for (int i = b0; i < b1; ++i) {
    int c = counts[i];
    row_start[i] = run;
    csr_src[run] = i;        // self-loop first
    cursor[i] = run + 1;
    dinv[i] = rsqrtf((float)c);
    run += c;
  }
  if (t == 255) row_start[Nn] = run;
}
__global__ void scatter_k(const int* __restrict__ srcv, const int* __restrict__ dstv, int E,
                          int* cursor, int* csr_src) {
  for (int e = blockIdx.x * blockDim.x + threadIdx.x; e < E; e += gridDim.x * blockDim.x) {
    int pos = atomicAdd(&cursor[dstv[e]], 1);
    csr_src[pos] = srcv[e];
  }
}

// ---------------- GATv2 fused single-pass, bf16, LDS edge list, exp2 softmax ----------
// per-dst block, 320 thr = 10 heads x 32 lanes; ushort2 gathers; att pre-scaled by log2e.
#define GAT_EDGE(U0, U1)                                                       \
  { float x0a, x0b, x1a, x1b;                                                  \
    bf2unpack(U0, x0a, x0b);                                                   \
    bf2unpack(U1, x1a, x1b);                                                   \
    float v, lv;                                                               \
    v = x0a + xr0a; lv = fmaxf(v, NEG * v); float p = at0a * lv;               \
    v = x0b + xr0b; lv = fmaxf(v, NEG * v); p += at0b * lv;                    \
    v = x1a + xr1a; lv = fmaxf(v, NEG * v); p += at1a * lv;                    \
    v = x1b + xr1b; lv = fmaxf(v, NEG * v); p += at1b * lv;                    \
    p += __shfl_xor(p, 16, 32);                                                \
    p += __shfl_xor(p, 8, 32);                                                 \
    p += __shfl_xor(p, 4, 32);                                                 \
    p += __shfl_xor(p, 2, 32);                                                 \
    p += __shfl_xor(p, 1, 32);                                                 \
    p = EXP2F(p);                                                              \
    denom += p;                                                                \
    acc0a += p * x0a;                                                          \
    acc0b += p * x0b;                                                          \
    acc1a += p * x1a;                                                          \
    acc1b += p * x1b; }

__global__ __launch_bounds__(320) void gatv2_fused_k(const __hip_bfloat16* __restrict__ xl,
                                                     const __hip_bfloat16* __restrict__ xr,
                                                     const float* __restrict__ att,
                                                     const float* __restrict__ b_gat,
                                                     const int* __restrict__ row_start,
                                                     const int* __restrict__ csr_src,
                                                     __hip_bfloat16* __restrict__ h1out) {
  __shared__ int eoff[ECAP];
  int dst = blockIdx.x;
  int t = threadIdx.x;
  int h = t >> 5, w = t & 31;
  int hb = h * CH;
  bool hasP1 = (w < 7);
  int c0 = hb + 2 * w;
  int c1 = hb + 64 + 2 * w;
  const unsigned short* xru = (const unsigned short*)xr + (size_t)dst * F;
  float xr0a, xr0b, xr1a, xr1b;
  bf2unpack(*(const unsigned int*)(xru + c0), xr0a, xr0b);
  {
    unsigned int u = hasP1 ? *(const unsigned int*)(xru + c1) : 0u;
    bf2unpack(u, xr1a, xr1b);
  }
  const float L2E = 1.4426950408889634f;
  float at0a = att[c0] * L2E, at0b = att[c0 + 1] * L2E;
  float at1a = hasP1 ? att[c1] * L2E : 0.f, at1b = hasP1 ? att[c1 + 1] * L2E : 0.f;
  int r0 = row_start[dst], r1 = row_start[dst + 1];
  float acc0a = 0.f, acc0b = 0.f, acc1a = 0.f, acc1b = 0.f, denom = 0.f;
  const unsigned short* xlu = (const unsigned short*)xl;

  for (int base = r0; base < r1; base += ECAP) {
    int cnt = min(ECAP, r1 - base);
    __syncthreads();
    for (int i = t; i < cnt; i += 320) eoff[i] = csr_src[base + i] * 780;
    __syncthreads();
    // depth-2 pipeline within chunk (wrap to 0; cnt >= 1)
    unsigned oA = (unsigned)eoff[0];
    unsigned oB = (unsigned)eoff[(1 < cnt) ? 1 : 0];
    unsigned int uA0 = *(const unsigned int*)(xlu + oA + c0);
    unsigned int uA1 = hasP1 ? *(const unsigned int*)(xlu + oA + c1) : 0u;
    unsigned int uB0 = *(const unsigned int*)(xlu + oB + c0);
    unsigned int uB1 = hasP1 ? *(const unsigned int*)(xlu + oB + c1) : 0u;
    int j = 0;
#pragma unroll 2
    for (; j + 1 < cnt; j += 2) {
      int j2 = j + 2; j2 = (j2 < cnt) ? j2 : 0;
      int j3 = j + 3; j3 = (j3 < cnt) ? j3 : 0;
      unsigned o2 = (unsigned)eoff[j2];
      unsigned o3 = (unsigned)eoff[j3];
      unsigned int uC0 = *(const unsigned int*)(xlu + o2 + c0);
      unsigned int uC1 = hasP1 ? *(const unsigned int*)(xlu + o2 + c1) : 0u;
      unsigned int uD0 = *(const unsigned int*)(xlu + o3 + c0);
      unsigned int uD1 = hasP1 ? *(const unsigned int*)(xlu + o3 + c1) : 0u;
      GAT_EDGE(uA0, uA1);
      GAT_EDGE(uB0, uB1);
      uA0 = uC0; uA1 = uC1;
      uB0 = uD0; uB1 = uD1;
    }
    if (cnt & 1) GAT_EDGE(uA0, uA1);
  }

  float inv = 1.f / denom;
  __hip_bfloat16* orow = h1out + (size_t)dst * KPAD;
  orow[c0] = __float2bfloat16(fmaxf(acc0a * inv + b_gat[c0], 0.f));
  orow[c0 + 1] = __float2bfloat16(fmaxf(acc0b * inv + b_gat[c0 + 1], 0.f));
  if (hasP1) {
    orow[c1] = __float2bfloat16(fmaxf(acc1a * inv + b_gat[c1], 0.f));
    orow[c1 + 1] = __float2bfloat16(fmaxf(acc1b * inv + b_gat[c1 + 1], 0.f));
  }
  if (t < KPAD - F) orow[F + t] = __float2bfloat16(0.f);
}

// ---------------- GCN aggregation, LDS edge list + staged norms, bf16 in/out ----------
#define AGG_EDGE(U0, U1, NV)                                                   \
  { float x0a, x0b, x1a, x1b;                                                  \
    bf2unpack(U0, x0a, x0b);                                                   \
    bf2unpack(U1, x1a, x1b);                                                   \
    a0a += (NV) * x0a;                                                         \
    a0b += (NV) * x0b;                                                         \
    a1a += (NV) * x1a;                                                         \
    a1b += (NV) * x1b; }

__global__ __launch_bounds__(320) void gcn_agg_k(const __hip_bfloat16* __restrict__ hmat,
                                                 const float* __restrict__ bias,
                                                 const int* __restrict__ row_start,
                                                 const int* __restrict__ csr_src,
                                                 const float* __restrict__ dinv,
                                                 __hip_bfloat16* __restrict__ out) {
  __shared__ int eoff[ECAP];
  __shared__ float enrm[ECAP];
  int dst = blockIdx.x;
  int t = threadIdx.x;
  bool hasP1 = (t < 70);
  int c0 = 2 * t;
  int c1 = 640 + 2 * t;
  int r0 = row_start[dst], r1 = row_start[dst + 1];
  float di = dinv[dst];
  float a0a = 0.f, a0b = 0.f, a1a = 0.f, a1b = 0.f;
  const unsigned short* hu = (const unsigned short*)hmat;

  for (int base = r0; base < r1; base += ECAP) {
    int cnt = min(ECAP, r1 - base);
    __syncthreads();
    for (int i = t; i < cnt; i += 320) {
      int s = csr_src[base + i];
      eoff[i] = s * 780;
      enrm[i] = di * dinv[s];
    }
    __syncthreads();
    unsigned oA = (unsigned)eoff[0];
    int jB0 = (1 < cnt) ? 1 : 0;
    unsigned oB = (unsigned)eoff[jB0];
    float nvA = enrm[0], nvB = enrm[jB0];
    unsigned int uA0 = *(const unsigned int*)(hu + oA + c0);
    unsigned int uA1 = hasP1 ? *(const unsigned int*)(hu + oA + c1) : 0u;
    unsigned int uB0 = *(const unsigned int*)(hu + oB + c0);
    unsigned int uB1 = hasP1 ? *(const unsigned int*)(hu + oB + c1) : 0u;
    int j = 0;
#pragma unroll 2
    for (; j + 1 < cnt; j += 2) {
      int j2 = j + 2; j2 = (j2 < cnt) ? j2 : 0;
      int j3 = j + 3; j3 = (j3 < cnt) ? j3 : 0;
      unsigned o2 = (unsigned)eoff[j2];
      unsigned o3 = (unsigned)eoff[j3];
      float nv2 = enrm[j2], nv3 = enrm[j3];
      unsigned int uC0 = *(const unsigned int*)(hu + o2 + c0);
      unsigned int uC1 = hasP1 ? *(const unsigned int*)(hu + o2 + c1) : 0u;
      unsigned int uD0 = *(const unsigned int*)(hu + o3 + c0);
      unsigned int uD1 = hasP1 ? *(const unsigned int*)(hu + o3 + c1) : 0u;
      AGG_EDGE(uA0, uA1, nvA);
      AGG_EDGE(uB0, uB1, nvB);
      uA0 = uC0; uA1 = uC1; nvA = nv2;
      uB0 = uD0; uB1 = uD1; nvB = nv3;
    }
    if (cnt & 1) AGG_EDGE(uA0, uA1, nvA);
  }

  __hip_bfloat16* o = out + (size_t)dst * F;
  o[c0] = __float2bfloat16(fmaxf(a0a + bias[c0], 0.f));
  o[c0 + 1] = __float2bfloat16(fmaxf(a0b + bias[c0 + 1], 0.f));
  if (hasP1) {
    o[c1] = __float2bfloat16(fmaxf(a1a + bias[c1], 0.f));
    o[c1 + 1] = __float2bfloat16(fmaxf(a1b + bias[c1 + 1], 0.f));
  }
}

// ---------------- pooling: bf16 in; per-graph max & mean; bf16 pooled [NGRAPH x K2PAD] ----
__global__ __launch_bounds__(320) void pool_k(const __hip_bfloat16* __restrict__ hmat,
                                              const int* __restrict__ batch,
                                              __hip_bfloat16* __restrict__ pooled, int Nn) {
  int g = blockIdx.x;
  int t = threadIdx.x;
  __shared__ int lo_s, hi_s;
  if (t == 0) {
    int lo = 0, hi = Nn;
    while (lo < hi) { int mid = (lo + hi) >> 1; if (batch[mid] < g) lo = mid + 1; else hi = mid; }
    lo_s = lo;
    int lo2 = lo, hi2 = Nn;
    while (lo2 < hi2) { int mid = (lo2 + hi2) >> 1; if (batch[mid] < g + 1) lo2 = mid + 1; else hi2 = mid; }
    hi_s = lo2;
  }
  __syncthreads();
  int lo = lo_s, hi = hi_s, cnt = hi - lo;
  bool hasP1 = (t < 70);
  int c0 = 2 * t;
  int c1 = 640 + 2 * t;
  float m0a = -1e30f, m0b = -1e30f, m1a = -1e30f, m1b = -1e30f;
  float s0a = 0.f, s0b = 0.f, s1a = 0.f, s1b = 0.f;
  const unsigned short* hu = (const unsigned short*)hmat;
  for (int n = lo; n < hi; ++n) {
    const unsigned short* hp = hu + (size_t)n * F;
    unsigned int u0 = *(const unsigned int*)(hp + c0);
    float v0x, v0y;
    bf2unpack(u0, v0x, v0y);
    m0a = fmaxf(m0a, v0x); s0a += v0x;
    m0b = fmaxf(m0b, v0y); s0b += v0y;
    if (hasP1) {
      unsigned int u1 = *(const unsigned int*)(hp + c1);
      float v1x, v1y;
      bf2unpack(u1, v1x, v1y);
      m1a = fmaxf(m1a, v1x); s1a += v1x;
      m1b = fmaxf(m1b, v1y); s1b += v1y;
    }
  }
  float inv = 1.f / (float)(cnt > 0 ? cnt : 1);
  __hip_bfloat16* o = pooled + (size_t)g * K2PAD;
  o[c0] = __float2bfloat16(cnt ? m0a : 0.f);
  o[c0 + 1] = __float2bfloat16(cnt ? m0b : 0.f);
  o[780 + c0] = __float2bfloat16(s0a * inv);
  o[780 + c0 + 1] = __float2bfloat16(s0b * inv);
  if (hasP1) {
    o[c1] = __float2bfloat16(cnt ? m1a : 0.f);
    o[c1 + 1] = __float2bfloat16(cnt ? m1b : 0.f);
    o[780 + c1] = __float2bfloat16(s1a * inv);
    o[780 + c1 + 1] = __float2bfloat16(s1b * inv);
  }
  if (t < K2PAD - 1560) o[1560 + t] = __float2bfloat16(0.f);
}

// ---------------- launcher ----------------
extern "C" void kernel_launch(void* const* d_in, const int* in_sizes, int n_in,
                              void* d_out, int out_size, void* d_ws, size_t ws_size,
                              hipStream_t stream) {
  const float* x     = (const float*)d_in[0];
  const int*   ei    = (const int*)d_in[1];
  const int*   batch = (const int*)d_in[2];
  const float* Wl    = (const float*)d_in[3];
  const float* Wr    = (const float*)d_in[4];
  const float* att   = (const float*)d_in[5];
  const float* b_gat = (const float*)d_in[6];
  const float* W_gcn = (const float*)d_in[7];
  const float* b_gcn = (const float*)d_in[8];
  const float* W_fc1 = (const float*)d_in[9];
  const float* b_fc1 = (const float*)d_in[10];
  const float* W_fc2 = (const float*)d_in[11];
  const float* b_fc2 = (const float*)d_in[12];
  float* out = (float*)d_out;

  int Nn = in_sizes[0] / 78;   // 16384
  int E  = in_sizes[1] / 2;    // 262144
  int EP = E + Nn;             // with self-loops
  const int* srcv = ei;
  const int* dstv = ei + E;

  // workspace layout
  char* wsb = (char*)d_ws;
  size_t NB = (size_t)Nn * F;
  __hip_bfloat16* xrb = (__hip_bfloat16*)wsb;                 // [Nn*F] bf16: xr; later aggbf
  __hip_bfloat16* aggbf = xrb;                                // alias (xr dead by then)
  wsb += NB * sizeof(__hip_bfloat16);
  __hip_bfloat16* bufBF = (__hip_bfloat16*)wsb;               // [Nn*F] bf16: xl, then h2
  wsb += NB * sizeof(__hip_bfloat16);
  __hip_bfloat16* h1bf = (__hip_bfloat16*)wsb;                // [Nn*KPAD] bf16: GAT out
  wsb += (size_t)Nn * KPAD * sizeof(__hip_bfloat16);
  __hip_bfloat16* xbf = (__hip_bfloat16*)wsb;                 // [Nn*K1] bf16
  wsb += (size_t)Nn * K1 * sizeof(__hip_bfloat16);
  __hip_bfloat16* Wlrb = (__hip_bfloat16*)wsb;                // [N1PAD*K1]
  wsb += (size_t)N1PAD * K1 * sizeof(__hip_bfloat16);
  __hip_bfloat16* Wtb = (__hip_bfloat16*)wsb;                 // [NPAD*KPAD]
  wsb += (size_t)NPAD * KPAD * sizeof(__hip_bfloat16);
  __hip_bfloat16* Wfc1b = (__hip_bfloat16*)wsb;               // [N2PAD*K2PAD]
  wsb += (size_t)N2PAD * K2PAD * sizeof(__hip_bfloat16);
  __hip_bfloat16* Wfc2b = (__hip_bfloat16*)wsb;               // [128*N2PAD]
  wsb += (size_t)128 * N2PAD * sizeof(__hip_bfloat16);
  __hip_bfloat16* pooledb = (__hip_bfloat16*)wsb;             // [NGRAPH*K2PAD]
  wsb += (size_t)NGRAPH * K2PAD * sizeof(__hip_bfloat16);
  __hip_bfloat16* g1b = (__hip_bfloat16*)wsb;                 // [NGRAPH*N2PAD] FC1 out
  wsb += (size_t)NGRAPH * N2PAD * sizeof(__hip_bfloat16);
  int* csr_src = (int*)wsb;      wsb += (size_t)EP * sizeof(int);
  int* counts = (int*)wsb;       wsb += (size_t)Nn * sizeof(int);
  int* row_start = (int*)wsb;    wsb += (size_t)(Nn + 1) * sizeof(int);
  int* cursor = (int*)wsb;       wsb += (size_t)Nn * sizeof(int);
  float* dinv = (float*)wsb;     wsb += (size_t)Nn * sizeof(float);
  size_t need = (size_t)(wsb - (char*)d_ws);
  if (need > ws_size) {
    fprintf(stderr, "kernel_launch: ws too small: need %zu have %zu\n", need, ws_size);
  }

  dim3 blk(256);

  // merged preprocessing: all casts + out=bias + counts=1
  int prep_total = Nn * K1 + N1PAD * K1 + NPAD * KPAD + N2PAD * K2PAD + 128 * N2PAD
                 + NGRAPH * 128 + Nn;
  prep_k<<<(prep_total + 255) / 256, 256, 0, stream>>>(x, Wl, Wr, W_gcn, W_fc1, W_fc2, b_fc2,
                                                       xbf, Wlrb, Wtb, Wfc1b, Wfc2b,
                                                       out, counts, Nn);

  // CSR by dst (self-loop slot first)
  count_k<<<512, 256, 0, stream>>>(dstv, E, counts);
  scan_k<<<1, 256, 0, stream>>>(counts, row_start, cursor, csr_src, dinv, Nn);
  scatter_k<<<512, 256, 0, stream>>>(srcv, dstv, E, cursor, csr_src);

  // transform GEMM (bf16 MFMA, BK=64): xbf @ Wlrb^T -> xl (bufBF) | xr (xrb), both bf16
  dim3 g1grid(N1PAD / 128, Nn / 128);
  gemm_bf16_dual_k<<<g1grid, blk, 0, stream>>>((const unsigned short*)xbf,
                                               (const unsigned short*)Wlrb,
                                               bufBF, xrb, Nn, N1, K1, K1);

  // GATv2 fused single-pass -> h1bf (bf16, KPAD stride, padded cols zeroed)
  gatv2_fused_k<<<Nn, 320, 0, stream>>>(bufBF, xrb, att, b_gat, row_start, csr_src, h1bf);

  // GCN matmul (bf16 MFMA, BK=64): h1bf @ Wtb^T -> h2 bf16 (bufBF, xl dead)
  dim3 g2grid(NPAD / 128, Nn / 128);
  gemm_bf16_obf_k<<<g2grid, blk, 0, stream>>>((const unsigned short*)h1bf,
                                              (const unsigned short*)Wtb,
                                              bufBF, Nn, F, KPAD, KPAD);

  // normalized aggregation (bf16 gather) -> bf16 aggbf (aliases dead xr)
  gcn_agg_k<<<Nn, 320, 0, stream>>>(bufBF, b_gcn, row_start, csr_src, dinv, aggbf);

  // pooling (bf16 in) -> bf16 pooled [NGRAPH x K2PAD], zero-padded
  pool_k<<<NGRAPH, 320, 0, stream>>>(aggbf, batch, pooledb, Nn);

  // FC1 (bf16 MFMA, BK=64): g1b = relu(pooled @ Wfc1b^T + b_fc1), bf16, padded to N2PAD
  dim3 fc1grid(N2PAD / 128, NGRAPH / 128);
  gemm_bf16_fc1_k<<<fc1grid, blk, 0, stream>>>((const unsigned short*)pooledb,
                                               (const unsigned short*)Wfc1b,
                                               b_fc1, g1b, NGRAPH, 1500, K2PAD, K2PAD);

  // FC2 (bf16 MFMA split-K): out += g1b @ Wfc2b^T (out pre-inited with b_fc2)
  dim3 fc2grid(1, NGRAPH / 128, 6);   // kchunk 256 -> 4 BK iters per block
  gemm_bf16_fc2_k<<<fc2grid, blk, 0, stream>>>((const unsigned short*)g1b,
                                               (const unsigned short*)Wfc2b,
                                               out, NGRAPH, 256);
}

// Round 13
// 529.939 us; speedup vs baseline: 1.0092x; 1.0092x over previous
//
#include <hip/hip_runtime.h>
#include <hip/hip_bf16.h>
#include <math.h>
#include <stdio.h>

#define HEADS 10
#define CH 78
#define F 780          // HEADS*CH
#define NGRAPH 512
#define NEG 0.2f
#define KPAD 832       // GCN GEMM K: 780 padded to mult of 64
#define NPAD 896       // GCN GEMM N: 780 padded to mult of 128
#define K1 128         // transform GEMM K: 78 padded to mult of 64
#define N1 1560        // transform GEMM N: 780 (xl) + 780 (xr)
#define N1PAD 1664     // 1560 padded to mult of 128
#define K2PAD 1600     // FC1 K: 1560 padded to mult of 64
#define N2PAD 1536     // FC1 N: 1500 padded to mult of 128 (also FC2 K with zero pad)

typedef __attribute__((ext_vector_type(8))) short short8;
typedef __attribute__((ext_vector_type(4))) float f32x4;

#if __has_builtin(__builtin_amdgcn_exp2f)
#define EXP2F(x) __builtin_amdgcn_exp2f(x)
#else
#define EXP2F(x) exp2f(x)
#endif

__device__ inline void bf2unpack(unsigned int u, float& lo, float& hi) {
  union { unsigned int ui; float f; } a, b;
  a.ui = u << 16;
  b.ui = u & 0xffff0000u;
  lo = a.f; hi = b.f;
}

// ---------------- merged preprocessing: casts + counts init + out init ----------
__global__ __launch_bounds__(256) void prep_k(const float* __restrict__ x,
                                              const float* __restrict__ Wl,
                                              const float* __restrict__ Wr,
                                              const float* __restrict__ Wgcn,
                                              const float* __restrict__ Wfc1,
                                              const float* __restrict__ Wfc2,
                                              const float* __restrict__ bfc2,
                                              __hip_bfloat16* __restrict__ xb,
                                              __hip_bfloat16* __restrict__ Wlrb,
                                              __hip_bfloat16* __restrict__ Wtb,
                                              __hip_bfloat16* __restrict__ Wfc1b,
                                              __hip_bfloat16* __restrict__ Wfc2b,
                                              float* __restrict__ outinit,
                                              int* __restrict__ counts, int Nn) {
  int i = blockIdx.x * 256 + threadIdx.x;
  int s0 = Nn * K1;
  int s1 = s0 + N1PAD * K1;
  int s2 = s1 + NPAD * KPAD;
  int s3 = s2 + N2PAD * K2PAD;
  int s4 = s3 + 128 * N2PAD;
  int s5 = s4 + NGRAPH * 128;
  int s6 = s5 + Nn;
  if (i < s0) {
    int row = i / K1, k = i - row * K1;
    xb[i] = __float2bfloat16((k < 78) ? x[(size_t)row * 78 + k] : 0.f);
  } else if (i < s1) {
    int j = i - s0;
    int n = j / K1, k = j - n * K1;
    float v = 0.f;
    if (k < 78 && n < N1) v = (n < F) ? Wl[(size_t)k * F + n] : Wr[(size_t)k * F + (n - F)];
    Wlrb[j] = __float2bfloat16(v);
  } else if (i < s2) {
    int j = i - s1;
    int n = j / KPAD, k = j - n * KPAD;
    float v = (n < F && k < F) ? Wgcn[(size_t)k * F + n] : 0.f;
    Wtb[j] = __float2bfloat16(v);
  } else if (i < s3) {
    int j = i - s2;
    int n = j / K2PAD, k = j - n * K2PAD;
    float v = (n < 1500 && k < 1560) ? Wfc1[(size_t)k * 1500 + n] : 0.f;
    Wfc1b[j] = __float2bfloat16(v);
  } else if (i < s4) {
    int j = i - s3;
    int n = j / N2PAD, k = j - n * N2PAD;     // n: out col 0..127, k: 0..1535
    float v = (k < 1500) ? Wfc2[(size_t)k * 128 + n] : 0.f;
    Wfc2b[j] = __float2bfloat16(v);
  } else if (i < s5) {
    int j = i - s4;
    outinit[j] = bfc2[j & 127];
  } else if (i < s6) {
    counts[i - s5] = 1;   // self-loop
  }
}

// ---------------- bf16 MFMA GEMM core, BK=64 ----------------
__device__ inline void gl_lds16(const unsigned short* g, unsigned short* l) {
  __builtin_amdgcn_global_load_lds(
      (const __attribute__((address_space(1))) unsigned int*)g,
      (__attribute__((address_space(3))) unsigned int*)l, 16, 0, 0);
}

// A: [M][lda] bf16 row-major, Bt: [Ncols_pad][lda] bf16 (B transposed). K mult of 64.
// 128x128 tile, 4 waves x (4x4) mfma_f32_16x16x32_bf16.
#define MFMA_CORE64(A, Bt, lda, K)                                                \
  __shared__ unsigned short As[128 * 64];                                         \
  __shared__ unsigned short Bs[128 * 64];                                         \
  int tid = threadIdx.x;                                                          \
  int wave = tid >> 6, lane = tid & 63;                                           \
  int m0 = blockIdx.y * 128, n0 = blockIdx.x * 128;                               \
  int wr = (wave >> 1) * 64, wc = (wave & 1) * 64;                                \
  f32x4 acc[4][4];                                                                \
  _Pragma("unroll")                                                               \
  for (int i = 0; i < 4; ++i)                                                     \
    _Pragma("unroll")                                                             \
    for (int j = 0; j < 4; ++j) acc[i][j] = (f32x4){0.f, 0.f, 0.f, 0.f};          \
  int lrow = lane >> 3;                                                           \
  int lcol = (lane & 7) * 8;                                                      \
  const unsigned short* gA0 = A + (size_t)(m0 + wave * 32 + lrow) * lda + lcol;   \
  const unsigned short* gB0 = Bt + (size_t)(n0 + wave * 32 + lrow) * lda + lcol;  \
  unsigned short* lA = As + (wave * 32) * 64;                                     \
  unsigned short* lB = Bs + (wave * 32) * 64;                                     \
  int q8 = (lane >> 4) * 8;                                                       \
  int fr = lane & 15;                                                             \
  for (int k0 = 0; k0 < K; k0 += 64) {                                            \
    _Pragma("unroll")                                                             \
    for (int c = 0; c < 4; ++c) {                                                 \
      gl_lds16(gA0 + (size_t)(8 * c) * lda, lA + (8 * c) * 64);                   \
      gl_lds16(gB0 + (size_t)(8 * c) * lda, lB + (8 * c) * 64);                   \
    }                                                                             \
    gA0 += 64; gB0 += 64;                                                         \
    __syncthreads();                                                              \
    _Pragma("unroll")                                                             \
    for (int ks = 0; ks < 64; ks += 32) {                                         \
      short8 a[4], b[4];                                                          \
      _Pragma("unroll")                                                           \
      for (int i = 0; i < 4; ++i) a[i] = *(const short8*)&As[(wr + 16 * i + fr) * 64 + ks + q8]; \
      _Pragma("unroll")                                                           \
      for (int j = 0; j < 4; ++j) b[j] = *(const short8*)&Bs[(wc + 16 * j + fr) * 64 + ks + q8]; \
      _Pragma("unroll")                                                           \
      for (int i = 0; i < 4; ++i)                                                 \
        _Pragma("unroll")                                                         \
        for (int j = 0; j < 4; ++j)                                               \
          acc[i][j] = __builtin_amdgcn_mfma_f32_16x16x32_bf16(a[i], b[j], acc[i][j], 0, 0, 0); \
    }                                                                             \
    __syncthreads();                                                              \
  }                                                                               \
  int cq = (lane >> 4) * 4;

// variant 1: dual bf16 output (cols < F -> Cl stride F; cols >= F -> Cr stride F)
__global__ __launch_bounds__(256) void gemm_bf16_dual_k(const unsigned short* __restrict__ A,
                                                        const unsigned short* __restrict__ Bt,
                                                        __hip_bfloat16* __restrict__ Cl,
                                                        __hip_bfloat16* __restrict__ Cr,
                                                        int M, int Ncols, int K, int lda) {
  MFMA_CORE64(A, Bt, lda, K)
#pragma unroll
  for (int i = 0; i < 4; ++i) {
#pragma unroll
    for (int j = 0; j < 4; ++j) {
      int col = n0 + wc + 16 * j + fr;
      if (col >= Ncols) continue;
      int rowb = m0 + wr + 16 * i + cq;
#pragma unroll
      for (int r = 0; r < 4; ++r) {
        int row = rowb + r;
        if (row >= M) continue;
        float v = acc[i][j][r];
        if (col < F) Cl[(size_t)row * F + col] = __float2bfloat16(v);
        else         Cr[(size_t)row * F + (col - F)] = __float2bfloat16(v);
      }
    }
  }
}

// variant 2: bf16 output, row stride Ncols
__global__ __launch_bounds__(256) void gemm_bf16_obf_k(const unsigned short* __restrict__ A,
                                                       const unsigned short* __restrict__ Bt,
                                                       __hip_bfloat16* __restrict__ C,
                                                       int M, int Ncols, int K, int lda) {
  MFMA_CORE64(A, Bt, lda, K)
#pragma unroll
  for (int i = 0; i < 4; ++i) {
#pragma unroll
    for (int j = 0; j < 4; ++j) {
      int col = n0 + wc + 16 * j + fr;
      if (col >= Ncols) continue;
      int rowb = m0 + wr + 16 * i + cq;
#pragma unroll
      for (int r = 0; r < 4; ++r) {
        int row = rowb + r;
        if (row < M) C[(size_t)row * Ncols + col] = __float2bfloat16(acc[i][j][r]);
      }
    }
  }
}

// variant 3 (FC1): bias+relu epilogue, bf16 output stride N2PAD, zero pad cols >= Nreal
__global__ __launch_bounds__(256) void gemm_bf16_fc1_k(const unsigned short* __restrict__ A,
                                                       const unsigned short* __restrict__ Bt,
                                                       const float* __restrict__ bias,
                                                       __hip_bfloat16* __restrict__ C,
                                                       int M, int Nreal, int K, int lda) {
  MFMA_CORE64(A, Bt, lda, K)
#pragma unroll
  for (int i = 0; i < 4; ++i) {
#pragma unroll
    for (int j = 0; j < 4; ++j) {
      int col = n0 + wc + 16 * j + fr;
      int rowb = m0 + wr + 16 * i + cq;
#pragma unroll
      for (int r = 0; r < 4; ++r) {
        int row = rowb + r;
        if (row >= M) continue;
        float v = 0.f;
        if (col < Nreal) v = fmaxf(acc[i][j][r] + bias[col], 0.f);
        C[(size_t)row * N2PAD + col] = __float2bfloat16(v);
      }
    }
  }
}

// variant 4 (FC2): split-K over blockIdx.z, f32 atomicAdd into pre-initialized C [M x 128]
__global__ __launch_bounds__(256) void gemm_bf16_fc2_k(const unsigned short* __restrict__ A,
                                                       const unsigned short* __restrict__ Bt,
                                                       float* C, int M, int kchunk) {
  const unsigned short* A2 = A + (size_t)blockIdx.z * kchunk;
  const unsigned short* B2 = Bt + (size_t)blockIdx.z * kchunk;
  MFMA_CORE64(A2, B2, N2PAD, kchunk)
#pragma unroll
  for (int i = 0; i < 4; ++i) {
#pragma unroll
    for (int j = 0; j < 4; ++j) {
      int col = n0 + wc + 16 * j + fr;   // n0 == 0, col < 128
      int rowb = m0 + wr + 16 * i + cq;
#pragma unroll
      for (int r = 0; r < 4; ++r) {
        int row = rowb + r;
        if (row < M && col < 128) atomicAdd(&C[(size_t)row * 128 + col], acc[i][j][r]);
      }
    }
  }
}

// ---------------- CSR build (by dst, self-loop first per node) ----------------
__global__ void count_k(const int* __restrict__ dstv, int E, int* counts) {
  for (int e = blockIdx.x * blockDim.x + threadIdx.x; e < E; e += gridDim.x * blockDim.x)
    atomicAdd(&counts[dstv[e]], 1);
}
// scan + node init fused: row_start, self-loop slot, cursor, dinv
__global__ __launch_bounds__(256) void scan_k(const int* __restrict__ counts,
                                              int* __restrict__ row_start,
                                              int* __restrict__ cursor,
                                              int* __restrict__ csr_src,
                                              float* __restrict__ dinv, int Nn) {
  __shared__ int part[256];
  int t = threadIdx.x;
  int chunk = (Nn + 255) / 256;
  int b0 = t * chunk, b1 = min(b0 + chunk, Nn);
  int s = 0;
  for (int i = b0; i < b1; ++i) s += counts[i];
  part[t] = s;
  __syncthreads();
  // Hillis-Steele inclusive scan over 256 partials
  for (int off = 1; off < 256; off <<= 1) {
    int u = (t >= off) ? part[t - off] : 0;
    __syncthreads();
    part[t] += u;
    __syncthreads();
  }
  int run = part[t] - s;   // exclusive prefix for this thread's chunk
  for (int i = b0; i < b1; ++i) {
    int c = counts[i];
    row_start[i] = run;
    csr_src[run] = i;        // self-loop first
    cursor[i] = run + 1;
    dinv[i] = rsqrtf((float)c);
    run += c;
  }
  if (t == 255) row_start[Nn] = run;
}
__global__ void scatter_k(const int* __restrict__ srcv, const int* __restrict__ dstv, int E,
                          int* cursor, int* csr_src) {
  for (int e = blockIdx.x * blockDim.x + threadIdx.x; e < E; e += gridDim.x * blockDim.x) {
    int pos = atomicAdd(&cursor[dstv[e]], 1);
    csr_src[pos] = srcv[e];
  }
}

// ---------------- GATv2 fused single-pass, bf16, pair-wise edge loop, exp2 softmax ----
// per-dst block, 320 thr = 10 heads x 32 lanes; ushort2 gathers; att pre-scaled by log2e.
#define GAT_EDGE(U0, U1)                                                       \
  { float x0a, x0b, x1a, x1b;                                                  \
    bf2unpack(U0, x0a, x0b);                                                   \
    bf2unpack(U1, x1a, x1b);                                                   \
    float v, lv;                                                               \
    v = x0a + xr0a; lv = fmaxf(v, NEG * v); float p = at0a * lv;               \
    v = x0b + xr0b; lv = fmaxf(v, NEG * v); p += at0b * lv;                    \
    v = x1a + xr1a; lv = fmaxf(v, NEG * v); p += at1a * lv;                    \
    v = x1b + xr1b; lv = fmaxf(v, NEG * v); p += at1b * lv;                    \
    p += __shfl_xor(p, 16, 32);                                                \
    p += __shfl_xor(p, 8, 32);                                                 \
    p += __shfl_xor(p, 4, 32);                                                 \
    p += __shfl_xor(p, 2, 32);                                                 \
    p += __shfl_xor(p, 1, 32);                                                 \
    p = EXP2F(p);                                                              \
    denom += p;                                                                \
    acc0a += p * x0a;                                                          \
    acc0b += p * x0b;                                                          \
    acc1a += p * x1a;                                                          \
    acc1b += p * x1b; }

__global__ __launch_bounds__(320) void gatv2_fused_k(const __hip_bfloat16* __restrict__ xl,
                                                     const __hip_bfloat16* __restrict__ xr,
                                                     const float* __restrict__ att,
                                                     const float* __restrict__ b_gat,
                                                     const int* __restrict__ row_start,
                                                     const int* __restrict__ csr_src,
                                                     __hip_bfloat16* __restrict__ h1out) {
  int dst = blockIdx.x;
  int t = threadIdx.x;
  int h = t >> 5, w = t & 31;
  int hb = h * CH;
  bool hasP1 = (w < 7);
  int c0 = hb + 2 * w;
  int c1 = hb + 64 + 2 * w;
  const unsigned short* xru = (const unsigned short*)xr + (size_t)dst * F;
  float xr0a, xr0b, xr1a, xr1b;
  bf2unpack(*(const unsigned int*)(xru + c0), xr0a, xr0b);
  {
    unsigned int u = hasP1 ? *(const unsigned int*)(xru + c1) : 0u;
    bf2unpack(u, xr1a, xr1b);
  }
  const float L2E = 1.4426950408889634f;
  float at0a = att[c0] * L2E, at0b = att[c0 + 1] * L2E;
  float at1a = hasP1 ? att[c1] * L2E : 0.f, at1b = hasP1 ? att[c1 + 1] * L2E : 0.f;
  int r0 = row_start[dst], r1 = row_start[dst + 1];
  float acc0a = 0.f, acc0b = 0.f, acc1a = 0.f, acc1b = 0.f, denom = 0.f;
  const unsigned short* xlu = (const unsigned short*)xl;

  // stage A = edge j, stage B = edge j+1 (wrap to r0; deg >= 1 via self-loop)
  unsigned int uA0, uA1, uB0, uB1;
  {
    unsigned oA = (unsigned)csr_src[r0] * 780u;
    uA0 = *(const unsigned int*)(xlu + oA + c0);
    uA1 = hasP1 ? *(const unsigned int*)(xlu + oA + c1) : 0u;
    int jB = (r0 + 1 < r1) ? r0 + 1 : r0;
    unsigned oB = (unsigned)csr_src[jB] * 780u;
    uB0 = *(const unsigned int*)(xlu + oB + c0);
    uB1 = hasP1 ? *(const unsigned int*)(xlu + oB + c1) : 0u;
  }
  int j = r0;
#pragma unroll 2
  for (; j + 1 < r1; j += 2) {
    int j2 = j + 2; j2 = (j2 < r1) ? j2 : r0;
    int j3 = j + 3; j3 = (j3 < r1) ? j3 : r0;
    unsigned o2 = (unsigned)csr_src[j2] * 780u;
    unsigned o3 = (unsigned)csr_src[j3] * 780u;
    unsigned int uC0 = *(const unsigned int*)(xlu + o2 + c0);
    unsigned int uC1 = hasP1 ? *(const unsigned int*)(xlu + o2 + c1) : 0u;
    unsigned int uD0 = *(const unsigned int*)(xlu + o3 + c0);
    unsigned int uD1 = hasP1 ? *(const unsigned int*)(xlu + o3 + c1) : 0u;
    GAT_EDGE(uA0, uA1);
    GAT_EDGE(uB0, uB1);
    uA0 = uC0; uA1 = uC1;
    uB0 = uD0; uB1 = uD1;
  }
  if ((r1 - r0) & 1) GAT_EDGE(uA0, uA1);

  float inv = 1.f / denom;
  __hip_bfloat16* orow = h1out + (size_t)dst * KPAD;
  orow[c0] = __float2bfloat16(fmaxf(acc0a * inv + b_gat[c0], 0.f));
  orow[c0 + 1] = __float2bfloat16(fmaxf(acc0b * inv + b_gat[c0 + 1], 0.f));
  if (hasP1) {
    orow[c1] = __float2bfloat16(fmaxf(acc1a * inv + b_gat[c1], 0.f));
    orow[c1 + 1] = __float2bfloat16(fmaxf(acc1b * inv + b_gat[c1 + 1], 0.f));
  }
  if (t < KPAD - F) orow[F + t] = __float2bfloat16(0.f);
}

// ---------------- GCN aggregation, pair-wise edge loop, bf16 in/out ----------------
#define AGG_EDGE(U0, U1, NV)                                                   \
  { float nrm = di * (NV);                                                     \
    float x0a, x0b, x1a, x1b;                                                  \
    bf2unpack(U0, x0a, x0b);                                                   \
    bf2unpack(U1, x1a, x1b);                                                   \
    a0a += nrm * x0a;                                                          \
    a0b += nrm * x0b;                                                          \
    a1a += nrm * x1a;                                                          \
    a1b += nrm * x1b; }

__global__ __launch_bounds__(320) void gcn_agg_k(const __hip_bfloat16* __restrict__ hmat,
                                                 const float* __restrict__ bias,
                                                 const int* __restrict__ row_start,
                                                 const int* __restrict__ csr_src,
                                                 const float* __restrict__ dinv,
                                                 __hip_bfloat16* __restrict__ out) {
  int dst = blockIdx.x;
  int t = threadIdx.x;
  bool hasP1 = (t < 70);
  int c0 = 2 * t;
  int c1 = 640 + 2 * t;
  int r0 = row_start[dst], r1 = row_start[dst + 1];
  float di = dinv[dst];
  float a0a = 0.f, a0b = 0.f, a1a = 0.f, a1b = 0.f;
  const unsigned short* hu = (const unsigned short*)hmat;

  unsigned int uA0, uA1, uB0, uB1;
  float nvA, nvB;
  {
    int sA = csr_src[r0];
    nvA = dinv[sA];
    unsigned oA = (unsigned)sA * 780u;
    uA0 = *(const unsigned int*)(hu + oA + c0);
    uA1 = hasP1 ? *(const unsigned int*)(hu + oA + c1) : 0u;
    int jB = (r0 + 1 < r1) ? r0 + 1 : r0;
    int sB = csr_src[jB];
    nvB = dinv[sB];
    unsigned oB = (unsigned)sB * 780u;
    uB0 = *(const unsigned int*)(hu + oB + c0);
    uB1 = hasP1 ? *(const unsigned int*)(hu + oB + c1) : 0u;
  }
  int j = r0;
#pragma unroll 2
  for (; j + 1 < r1; j += 2) {
    int j2 = j + 2; j2 = (j2 < r1) ? j2 : r0;
    int j3 = j + 3; j3 = (j3 < r1) ? j3 : r0;
    int s2 = csr_src[j2];
    int s3 = csr_src[j3];
    float nv2 = dinv[s2];
    float nv3 = dinv[s3];
    unsigned o2 = (unsigned)s2 * 780u;
    unsigned o3 = (unsigned)s3 * 780u;
    unsigned int uC0 = *(const unsigned int*)(hu + o2 + c0);
    unsigned int uC1 = hasP1 ? *(const unsigned int*)(hu + o2 + c1) : 0u;
    unsigned int uD0 = *(const unsigned int*)(hu + o3 + c0);
    unsigned int uD1 = hasP1 ? *(const unsigned int*)(hu + o3 + c1) : 0u;
    AGG_EDGE(uA0, uA1, nvA);
    AGG_EDGE(uB0, uB1, nvB);
    uA0 = uC0; uA1 = uC1; nvA = nv2;
    uB0 = uD0; uB1 = uD1; nvB = nv3;
  }
  if ((r1 - r0) & 1) AGG_EDGE(uA0, uA1, nvA);

  __hip_bfloat16* o = out + (size_t)dst * F;
  o[c0] = __float2bfloat16(fmaxf(a0a + bias[c0], 0.f));
  o[c0 + 1] = __float2bfloat16(fmaxf(a0b + bias[c0 + 1], 0.f));
  if (hasP1) {
    o[c1] = __float2bfloat16(fmaxf(a1a + bias[c1], 0.f));
    o[c1 + 1] = __float2bfloat16(fmaxf(a1b + bias[c1 + 1], 0.f));
  }
}

// ---------------- pooling: bf16 in; per-graph max & mean; bf16 pooled [NGRAPH x K2PAD] ----
__global__ __launch_bounds__(320) void pool_k(const __hip_bfloat16* __restrict__ hmat,
                                              const int* __restrict__ batch,
                                              __hip_bfloat16* __restrict__ pooled, int Nn) {
  int g = blockIdx.x;
  int t = threadIdx.x;
  __shared__ int lo_s, hi_s;
  if (t == 0) {
    int lo = 0, hi = Nn;
    while (lo < hi) { int mid = (lo + hi) >> 1; if (batch[mid] < g) lo = mid + 1; else hi = mid; }
    lo_s = lo;
    int lo2 = lo, hi2 = Nn;
    while (lo2 < hi2) { int mid = (lo2 + hi2) >> 1; if (batch[mid] < g + 1) lo2 = mid + 1; else hi2 = mid; }
    hi_s = lo2;
  }
  __syncthreads();
  int lo = lo_s, hi = hi_s, cnt = hi - lo;
  bool hasP1 = (t < 70);
  int c0 = 2 * t;
  int c1 = 640 + 2 * t;
  float m0a = -1e30f, m0b = -1e30f, m1a = -1e30f, m1b = -1e30f;
  float s0a = 0.f, s0b = 0.f, s1a = 0.f, s1b = 0.f;
  const unsigned short* hu = (const unsigned short*)hmat;
  for (int n = lo; n < hi; ++n) {
    const unsigned short* hp = hu + (size_t)n * F;
    unsigned int u0 = *(const unsigned int*)(hp + c0);
    float v0x, v0y;
    bf2unpack(u0, v0x, v0y);
    m0a = fmaxf(m0a, v0x); s0a += v0x;
    m0b = fmaxf(m0b, v0y); s0b += v0y;
    if (hasP1) {
      unsigned int u1 = *(const unsigned int*)(hp + c1);
      float v1x, v1y;
      bf2unpack(u1, v1x, v1y);
      m1a = fmaxf(m1a, v1x); s1a += v1x;
      m1b = fmaxf(m1b, v1y); s1b += v1y;
    }
  }
  float inv = 1.f / (float)(cnt > 0 ? cnt : 1);
  __hip_bfloat16* o = pooled + (size_t)g * K2PAD;
  o[c0] = __float2bfloat16(cnt ? m0a : 0.f);
  o[c0 + 1] = __float2bfloat16(cnt ? m0b : 0.f);
  o[780 + c0] = __float2bfloat16(s0a * inv);
  o[780 + c0 + 1] = __float2bfloat16(s0b * inv);
  if (hasP1) {
    o[c1] = __float2bfloat16(cnt ? m1a : 0.f);
    o[c1 + 1] = __float2bfloat16(cnt ? m1b : 0.f);
    o[780 + c1] = __float2bfloat16(s1a * inv);
    o[780 + c1 + 1] = __float2bfloat16(s1b * inv);
  }
  if (t < K2PAD - 1560) o[1560 + t] = __float2bfloat16(0.f);
}

// ---------------- launcher ----------------
extern "C" void kernel_launch(void* const* d_in, const int* in_sizes, int n_in,
                              void* d_out, int out_size, void* d_ws, size_t ws_size,
                              hipStream_t stream) {
  const float* x     = (const float*)d_in[0];
  const int*   ei    = (const int*)d_in[1];
  const int*   batch = (const int*)d_in[2];
  const float* Wl    = (const float*)d_in[3];
  const float* Wr    = (const float*)d_in[4];
  const float* att   = (const float*)d_in[5];
  const float* b_gat = (const float*)d_in[6];
  const float* W_gcn = (const float*)d_in[7];
  const float* b_gcn = (const float*)d_in[8];
  const float* W_fc1 = (const float*)d_in[9];
  const float* b_fc1 = (const float*)d_in[10];
  const float* W_fc2 = (const float*)d_in[11];
  const float* b_fc2 = (const float*)d_in[12];
  float* out = (float*)d_out;

  int Nn = in_sizes[0] / 78;   // 16384
  int E  = in_sizes[1] / 2;    // 262144
  int EP = E + Nn;             // with self-loops
  const int* srcv = ei;
  const int* dstv = ei + E;

  // workspace layout
  char* wsb = (char*)d_ws;
  size_t NB = (size_t)Nn * F;
  __hip_bfloat16* xrb = (__hip_bfloat16*)wsb;                 // [Nn*F] bf16: xr; later aggbf
  __hip_bfloat16* aggbf = xrb;                                // alias (xr dead by then)
  wsb += NB * sizeof(__hip_bfloat16);
  __hip_bfloat16* bufBF = (__hip_bfloat16*)wsb;               // [Nn*F] bf16: xl, then h2
  wsb += NB * sizeof(__hip_bfloat16);
  __hip_bfloat16* h1bf = (__hip_bfloat16*)wsb;                // [Nn*KPAD] bf16: GAT out
  wsb += (size_t)Nn * KPAD * sizeof(__hip_bfloat16);
  __hip_bfloat16* xbf = (__hip_bfloat16*)wsb;                 // [Nn*K1] bf16
  wsb += (size_t)Nn * K1 * sizeof(__hip_bfloat16);
  __hip_bfloat16* Wlrb = (__hip_bfloat16*)wsb;                // [N1PAD*K1]
  wsb += (size_t)N1PAD * K1 * sizeof(__hip_bfloat16);
  __hip_bfloat16* Wtb = (__hip_bfloat16*)wsb;                 // [NPAD*KPAD]
  wsb += (size_t)NPAD * KPAD * sizeof(__hip_bfloat16);
  __hip_bfloat16* Wfc1b = (__hip_bfloat16*)wsb;               // [N2PAD*K2PAD]
  wsb += (size_t)N2PAD * K2PAD * sizeof(__hip_bfloat16);
  __hip_bfloat16* Wfc2b = (__hip_bfloat16*)wsb;               // [128*N2PAD]
  wsb += (size_t)128 * N2PAD * sizeof(__hip_bfloat16);
  __hip_bfloat16* pooledb = (__hip_bfloat16*)wsb;             // [NGRAPH*K2PAD]
  wsb += (size_t)NGRAPH * K2PAD * sizeof(__hip_bfloat16);
  __hip_bfloat16* g1b = (__hip_bfloat16*)wsb;                 // [NGRAPH*N2PAD] FC1 out
  wsb += (size_t)NGRAPH * N2PAD * sizeof(__hip_bfloat16);
  int* csr_src = (int*)wsb;      wsb += (size_t)EP * sizeof(int);
  int* counts = (int*)wsb;       wsb += (size_t)Nn * sizeof(int);
  int* row_start = (int*)wsb;    wsb += (size_t)(Nn + 1) * sizeof(int);
  int* cursor = (int*)wsb;       wsb += (size_t)Nn * sizeof(int);
  float* dinv = (float*)wsb;     wsb += (size_t)Nn * sizeof(float);
  size_t need = (size_t)(wsb - (char*)d_ws);
  if (need > ws_size) {
    fprintf(stderr, "kernel_launch: ws too small: need %zu have %zu\n", need, ws_size);
  }

  dim3 blk(256);

  // merged preprocessing: all casts + out=bias + counts=1
  int prep_total = Nn * K1 + N1PAD * K1 + NPAD * KPAD + N2PAD * K2PAD + 128 * N2PAD
                 + NGRAPH * 128 + Nn;
  prep_k<<<(prep_total + 255) / 256, 256, 0, stream>>>(x, Wl, Wr, W_gcn, W_fc1, W_fc2, b_fc2,
                                                       xbf, Wlrb, Wtb, Wfc1b, Wfc2b,
                                                       out, counts, Nn);

  // CSR by dst (self-loop slot first)
  count_k<<<512, 256, 0, stream>>>(dstv, E, counts);
  scan_k<<<1, 256, 0, stream>>>(counts, row_start, cursor, csr_src, dinv, Nn);
  scatter_k<<<512, 256, 0, stream>>>(srcv, dstv, E, cursor, csr_src);

  // transform GEMM (bf16 MFMA, BK=64): xbf @ Wlrb^T -> xl (bufBF) | xr (xrb), both bf16
  dim3 g1grid(N1PAD / 128, Nn / 128);
  gemm_bf16_dual_k<<<g1grid, blk, 0, stream>>>((const unsigned short*)xbf,
                                               (const unsigned short*)Wlrb,
                                               bufBF, xrb, Nn, N1, K1, K1);

  // GATv2 fused single-pass -> h1bf (bf16, KPAD stride, padded cols zeroed)
  gatv2_fused_k<<<Nn, 320, 0, stream>>>(bufBF, xrb, att, b_gat, row_start, csr_src, h1bf);

  // GCN matmul (bf16 MFMA, BK=64): h1bf @ Wtb^T -> h2 bf16 (bufBF, xl dead)
  dim3 g2grid(NPAD / 128, Nn / 128);
  gemm_bf16_obf_k<<<g2grid, blk, 0, stream>>>((const unsigned short*)h1bf,
                                              (const unsigned short*)Wtb,
                                              bufBF, Nn, F, KPAD, KPAD);

  // normalized aggregation (bf16 gather) -> bf16 aggbf (aliases dead xr)
  gcn_agg_k<<<Nn, 320, 0, stream>>>(bufBF, b_gcn, row_start, csr_src, dinv, aggbf);

  // pooling (bf16 in) -> bf16 pooled [NGRAPH x K2PAD], zero-padded
  pool_k<<<NGRAPH, 320, 0, stream>>>(aggbf, batch, pooledb, Nn);

  // FC1 (bf16 MFMA, BK=64): g1b = relu(pooled @ Wfc1b^T + b_fc1), bf16, padded to N2PAD
  dim3 fc1grid(N2PAD / 128, NGRAPH / 128);
  gemm_bf16_fc1_k<<<fc1grid, blk, 0, stream>>>((const unsigned short*)pooledb,
                                               (const unsigned short*)Wfc1b,
                                               b_fc1, g1b, NGRAPH, 1500, K2PAD, K2PAD);

  // FC2 (bf16 MFMA split-K): out += g1b @ Wfc2b^T (out pre-inited with b_fc2)
  dim3 fc2grid(1, NGRAPH / 128, 6);   // kchunk 256 -> 4 BK iters per block
  gemm_bf16_fc2_k<<<fc2grid, blk, 0, stream>>>((const unsigned short*)g1b,
                                               (const unsigned short*)Wfc2b,
                                               out, NGRAPH, 256);
}

// Round 14
// 527.540 us; speedup vs baseline: 1.0138x; 1.0045x over previous
//
#include <hip/hip_runtime.h>
#include <hip/hip_bf16.h>
#include <math.h>
#include <stdio.h>

#define HEADS 10
#define CH 78
#define F 780          // HEADS*CH
#define NGRAPH 512
#define NEG 0.2f
#define KPAD 832       // GCN GEMM K: 780 padded to mult of 64
#define NPAD 896       // GCN GEMM N: 780 padded to mult of 128
#define K1 128         // transform GEMM K: 78 padded to mult of 64
#define N1 1560        // transform GEMM N: 780 (xl) + 780 (xr)
#define N1PAD 1664     // 1560 padded to mult of 128
#define K2PAD 1600     // FC1 K: 1560 padded to mult of 64
#define N2PAD 1536     // FC1 N: 1500 padded to mult of 128 (also FC2 K with zero pad)

typedef __attribute__((ext_vector_type(8))) short short8;
typedef __attribute__((ext_vector_type(4))) float f32x4;

__device__ inline void bf2unpack(unsigned int u, float& lo, float& hi) {
  union { unsigned int ui; float f; } a, b;
  a.ui = u << 16;
  b.ui = u & 0xffff0000u;
  lo = a.f; hi = b.f;
}

// ---------------- merged preprocessing: casts + counts init + out init ----------
__global__ __launch_bounds__(256) void prep_k(const float* __restrict__ x,
                                              const float* __restrict__ Wl,
                                              const float* __restrict__ Wr,
                                              const float* __restrict__ Wgcn,
                                              const float* __restrict__ Wfc1,
                                              const float* __restrict__ Wfc2,
                                              const float* __restrict__ bfc2,
                                              __hip_bfloat16* __restrict__ xb,
                                              __hip_bfloat16* __restrict__ Wlrb,
                                              __hip_bfloat16* __restrict__ Wtb,
                                              __hip_bfloat16* __restrict__ Wfc1b,
                                              __hip_bfloat16* __restrict__ Wfc2b,
                                              float* __restrict__ outinit,
                                              int* __restrict__ counts, int Nn) {
  int i = blockIdx.x * 256 + threadIdx.x;
  int s0 = Nn * K1;
  int s1 = s0 + N1PAD * K1;
  int s2 = s1 + NPAD * KPAD;
  int s3 = s2 + N2PAD * K2PAD;
  int s4 = s3 + 128 * N2PAD;
  int s5 = s4 + NGRAPH * 128;
  int s6 = s5 + Nn;
  if (i < s0) {
    int row = i / K1, k = i - row * K1;
    xb[i] = __float2bfloat16((k < 78) ? x[(size_t)row * 78 + k] : 0.f);
  } else if (i < s1) {
    int j = i - s0;
    int n = j / K1, k = j - n * K1;
    float v = 0.f;
    if (k < 78 && n < N1) v = (n < F) ? Wl[(size_t)k * F + n] : Wr[(size_t)k * F + (n - F)];
    Wlrb[j] = __float2bfloat16(v);
  } else if (i < s2) {
    int j = i - s1;
    int n = j / KPAD, k = j - n * KPAD;
    float v = (n < F && k < F) ? Wgcn[(size_t)k * F + n] : 0.f;
    Wtb[j] = __float2bfloat16(v);
  } else if (i < s3) {
    int j = i - s2;
    int n = j / K2PAD, k = j - n * K2PAD;
    float v = (n < 1500 && k < 1560) ? Wfc1[(size_t)k * 1500 + n] : 0.f;
    Wfc1b[j] = __float2bfloat16(v);
  } else if (i < s4) {
    int j = i - s3;
    int n = j / N2PAD, k = j - n * N2PAD;     // n: out col 0..127, k: 0..1535
    float v = (k < 1500) ? Wfc2[(size_t)k * 128 + n] : 0.f;
    Wfc2b[j] = __float2bfloat16(v);
  } else if (i < s5) {
    int j = i - s4;
    outinit[j] = bfc2[j & 127];
  } else if (i < s6) {
    counts[i - s5] = 1;   // self-loop
  }
}

// ---------------- bf16 MFMA GEMM core, BK=64 ----------------
__device__ inline void gl_lds16(const unsigned short* g, unsigned short* l) {
  __builtin_amdgcn_global_load_lds(
      (const __attribute__((address_space(1))) unsigned int*)g,
      (__attribute__((address_space(3))) unsigned int*)l, 16, 0, 0);
}

// A: [M][lda] bf16 row-major, Bt: [Ncols_pad][lda] bf16 (B transposed). K mult of 64.
// 128x128 tile, 4 waves x (4x4) mfma_f32_16x16x32_bf16.
#define MFMA_CORE64(A, Bt, lda, K)                                                \
  __shared__ unsigned short As[128 * 64];                                         \
  __shared__ unsigned short Bs[128 * 64];                                         \
  int tid = threadIdx.x;                                                          \
  int wave = tid >> 6, lane = tid & 63;                                           \
  int m0 = blockIdx.y * 128, n0 = blockIdx.x * 128;                               \
  int wr = (wave >> 1) * 64, wc = (wave & 1) * 64;                                \
  f32x4 acc[4][4];                                                                \
  _Pragma("unroll")                                                               \
  for (int i = 0; i < 4; ++i)                                                     \
    _Pragma("unroll")                                                             \
    for (int j = 0; j < 4; ++j) acc[i][j] = (f32x4){0.f, 0.f, 0.f, 0.f};          \
  int lrow = lane >> 3;                                                           \
  int lcol = (lane & 7) * 8;                                                      \
  const unsigned short* gA0 = A + (size_t)(m0 + wave * 32 + lrow) * lda + lcol;   \
  const unsigned short* gB0 = Bt + (size_t)(n0 + wave * 32 + lrow) * lda + lcol;  \
  unsigned short* lA = As + (wave * 32) * 64;                                     \
  unsigned short* lB = Bs + (wave * 32) * 64;                                     \
  int q8 = (lane >> 4) * 8;                                                       \
  int fr = lane & 15;                                                             \
  for (int k0 = 0; k0 < K; k0 += 64) {                                            \
    _Pragma("unroll")                                                             \
    for (int c = 0; c < 4; ++c) {                                                 \
      gl_lds16(gA0 + (size_t)(8 * c) * lda, lA + (8 * c) * 64);                   \
      gl_lds16(gB0 + (size_t)(8 * c) * lda, lB + (8 * c) * 64);                   \
    }                                                                             \
    gA0 += 64; gB0 += 64;                                                         \
    __syncthreads();                                                              \
    _Pragma("unroll")                                                             \
    for (int ks = 0; ks < 64; ks += 32) {                                         \
      short8 a[4], b[4];                                                          \
      _Pragma("unroll")                                                           \
      for (int i = 0; i < 4; ++i) a[i] = *(const short8*)&As[(wr + 16 * i + fr) * 64 + ks + q8]; \
      _Pragma("unroll")                                                           \
      for (int j = 0; j < 4; ++j) b[j] = *(const short8*)&Bs[(wc + 16 * j + fr) * 64 + ks + q8]; \
      _Pragma("unroll")                                                           \
      for (int i = 0; i < 4; ++i)                                                 \
        _Pragma("unroll")                                                         \
        for (int j = 0; j < 4; ++j)                                               \
          acc[i][j] = __builtin_amdgcn_mfma_f32_16x16x32_bf16(a[i], b[j], acc[i][j], 0, 0, 0); \
    }                                                                             \
    __syncthreads();                                                              \
  }                                                                               \
  int cq = (lane >> 4) * 4;

// variant 1: dual bf16 output (cols < F -> Cl stride F; cols >= F -> Cr stride F)
__global__ __launch_bounds__(256) void gemm_bf16_dual_k(const unsigned short* __restrict__ A,
                                                        const unsigned short* __restrict__ Bt,
                                                        __hip_bfloat16* __restrict__ Cl,
                                                        __hip_bfloat16* __restrict__ Cr,
                                                        int M, int Ncols, int K, int lda) {
  MFMA_CORE64(A, Bt, lda, K)
#pragma unroll
  for (int i = 0; i < 4; ++i) {
#pragma unroll
    for (int j = 0; j < 4; ++j) {
      int col = n0 + wc + 16 * j + fr;
      if (col >= Ncols) continue;
      int rowb = m0 + wr + 16 * i + cq;
#pragma unroll
      for (int r = 0; r < 4; ++r) {
        int row = rowb + r;
        if (row >= M) continue;
        float v = acc[i][j][r];
        if (col < F) Cl[(size_t)row * F + col] = __float2bfloat16(v);
        else         Cr[(size_t)row * F + (col - F)] = __float2bfloat16(v);
      }
    }
  }
}

// variant 2: bf16 output, row stride Ncols
__global__ __launch_bounds__(256) void gemm_bf16_obf_k(const unsigned short* __restrict__ A,
                                                       const unsigned short* __restrict__ Bt,
                                                       __hip_bfloat16* __restrict__ C,
                                                       int M, int Ncols, int K, int lda) {
  MFMA_CORE64(A, Bt, lda, K)
#pragma unroll
  for (int i = 0; i < 4; ++i) {
#pragma unroll
    for (int j = 0; j < 4; ++j) {
      int col = n0 + wc + 16 * j + fr;
      if (col >= Ncols) continue;
      int rowb = m0 + wr + 16 * i + cq;
#pragma unroll
      for (int r = 0; r < 4; ++r) {
        int row = rowb + r;
        if (row < M) C[(size_t)row * Ncols + col] = __float2bfloat16(acc[i][j][r]);
      }
    }
  }
}

// variant 3 (FC1): bias+relu epilogue, bf16 output stride N2PAD, zero pad cols >= Nreal
__global__ __launch_bounds__(256) void gemm_bf16_fc1_k(const unsigned short* __restrict__ A,
                                                       const unsigned short* __restrict__ Bt,
                                                       const float* __restrict__ bias,
                                                       __hip_bfloat16* __restrict__ C,
                                                       int M, int Nreal, int K, int lda) {
  MFMA_CORE64(A, Bt, lda, K)
#pragma unroll
  for (int i = 0; i < 4; ++i) {
#pragma unroll
    for (int j = 0; j < 4; ++j) {
      int col = n0 + wc + 16 * j + fr;
      int rowb = m0 + wr + 16 * i + cq;
#pragma unroll
      for (int r = 0; r < 4; ++r) {
        int row = rowb + r;
        if (row >= M) continue;
        float v = 0.f;
        if (col < Nreal) v = fmaxf(acc[i][j][r] + bias[col], 0.f);
        C[(size_t)row * N2PAD + col] = __float2bfloat16(v);
      }
    }
  }
}

// variant 4 (FC2): split-K over blockIdx.z, f32 atomicAdd into pre-initialized C [M x 128]
__global__ __launch_bounds__(256) void gemm_bf16_fc2_k(const unsigned short* __restrict__ A,
                                                       const unsigned short* __restrict__ Bt,
                                                       float* C, int M, int kchunk) {
  const unsigned short* A2 = A + (size_t)blockIdx.z * kchunk;
  const unsigned short* B2 = Bt + (size_t)blockIdx.z * kchunk;
  MFMA_CORE64(A2, B2, N2PAD, kchunk)
#pragma unroll
  for (int i = 0; i < 4; ++i) {
#pragma unroll
    for (int j = 0; j < 4; ++j) {
      int col = n0 + wc + 16 * j + fr;   // n0 == 0, col < 128
      int rowb = m0 + wr + 16 * i + cq;
#pragma unroll
      for (int r = 0; r < 4; ++r) {
        int row = rowb + r;
        if (row < M && col < 128) atomicAdd(&C[(size_t)row * 128 + col], acc[i][j][r]);
      }
    }
  }
}

// ---------------- CSR build (by dst, self-loop first per node) ----------------
__global__ void count_k(const int* __restrict__ dstv, int E, int* counts) {
  for (int e = blockIdx.x * blockDim.x + threadIdx.x; e < E; e += gridDim.x * blockDim.x)
    atomicAdd(&counts[dstv[e]], 1);
}
// scan + node init fused: row_start, self-loop slot, cursor, dinv
__global__ __launch_bounds__(256) void scan_k(const int* __restrict__ counts,
                                              int* __restrict__ row_start,
                                              int* __restrict__ cursor,
                                              int* __restrict__ csr_src,
                                              float* __restrict__ dinv, int Nn) {
  __shared__ int part[256];
  int t = threadIdx.x;
  int chunk = (Nn + 255) / 256;
  int b0 = t * chunk, b1 = min(b0 + chunk, Nn);
  int s = 0;
  for (int i = b0; i < b1; ++i) s += counts[i];
  part[t] = s;
  __syncthreads();
  // Hillis-Steele inclusive scan over 256 partials
  for (int off = 1; off < 256; off <<= 1) {
    int u = (t >= off) ? part[t - off] : 0;
    __syncthreads();
    part[t] += u;
    __syncthreads();
  }
  int run = part[t] - s;   // exclusive prefix for this thread's chunk
  for (int i = b0; i < b1; ++i) {
    int c = counts[i];
    row_start[i] = run;
    csr_src[run] = i;        // self-loop first
    cursor[i] = run + 1;
    dinv[i] = rsqrtf((float)c);
    run += c;
  }
  if (t == 255) row_start[Nn] = run;
}
__global__ void scatter_k(const int* __restrict__ srcv, const int* __restrict__ dstv, int E,
                          int* cursor, int* csr_src) {
  for (int e = blockIdx.x * blockDim.x + threadIdx.x; e < E; e += gridDim.x * blockDim.x) {
    int pos = atomicAdd(&cursor[dstv[e]], 1);
    csr_src[pos] = srcv[e];
  }
}

// ---------------- GATv2 fused single-pass, bf16, pair-wise edge loop (R11-proven) ----
// per-dst block, 320 thr = 10 heads x 32 lanes; ushort2 gathers; xr in bf16.
#define GAT_EDGE(U0, U1)                                                       \
  { float x0a, x0b, x1a, x1b;                                                  \
    bf2unpack(U0, x0a, x0b);                                                   \
    bf2unpack(U1, x1a, x1b);                                                   \
    float v, lv;                                                               \
    v = x0a + xr0a; lv = fmaxf(v, NEG * v); float p = at0a * lv;               \
    v = x0b + xr0b; lv = fmaxf(v, NEG * v); p += at0b * lv;                    \
    v = x1a + xr1a; lv = fmaxf(v, NEG * v); p += at1a * lv;                    \
    v = x1b + xr1b; lv = fmaxf(v, NEG * v); p += at1b * lv;                    \
    p += __shfl_xor(p, 16, 32);                                                \
    p += __shfl_xor(p, 8, 32);                                                 \
    p += __shfl_xor(p, 4, 32);                                                 \
    p += __shfl_xor(p, 2, 32);                                                 \
    p += __shfl_xor(p, 1, 32);                                                 \
    p = __expf(p);                                                             \
    denom += p;                                                                \
    acc0a += p * x0a;                                                          \
    acc0b += p * x0b;                                                          \
    acc1a += p * x1a;                                                          \
    acc1b += p * x1b; }

__global__ __launch_bounds__(320) void gatv2_fused_k(const __hip_bfloat16* __restrict__ xl,
                                                     const __hip_bfloat16* __restrict__ xr,
                                                     const float* __restrict__ att,
                                                     const float* __restrict__ b_gat,
                                                     const int* __restrict__ row_start,
                                                     const int* __restrict__ csr_src,
                                                     __hip_bfloat16* __restrict__ h1out) {
  int dst = blockIdx.x;
  int t = threadIdx.x;
  int h = t >> 5, w = t & 31;
  int hb = h * CH;
  bool hasP1 = (w < 7);
  int c0 = hb + 2 * w;
  int c1 = hb + 64 + 2 * w;
  const unsigned short* xru = (const unsigned short*)xr + (size_t)dst * F;
  float xr0a, xr0b, xr1a, xr1b;
  bf2unpack(*(const unsigned int*)(xru + c0), xr0a, xr0b);
  {
    unsigned int u = hasP1 ? *(const unsigned int*)(xru + c1) : 0u;
    bf2unpack(u, xr1a, xr1b);
  }
  float at0a = att[c0], at0b = att[c0 + 1];
  float at1a = hasP1 ? att[c1] : 0.f, at1b = hasP1 ? att[c1 + 1] : 0.f;
  int r0 = row_start[dst], r1 = row_start[dst + 1];
  float acc0a = 0.f, acc0b = 0.f, acc1a = 0.f, acc1b = 0.f, denom = 0.f;
  const unsigned short* xlu = (const unsigned short*)xl;

  // stage A = edge j, stage B = edge j+1 (wrap to r0; deg >= 1 via self-loop)
  unsigned int uA0, uA1, uB0, uB1;
  {
    unsigned oA = (unsigned)csr_src[r0] * 780u;
    uA0 = *(const unsigned int*)(xlu + oA + c0);
    uA1 = hasP1 ? *(const unsigned int*)(xlu + oA + c1) : 0u;
    int jB = (r0 + 1 < r1) ? r0 + 1 : r0;
    unsigned oB = (unsigned)csr_src[jB] * 780u;
    uB0 = *(const unsigned int*)(xlu + oB + c0);
    uB1 = hasP1 ? *(const unsigned int*)(xlu + oB + c1) : 0u;
  }
  int j = r0;
#pragma unroll 2
  for (; j + 1 < r1; j += 2) {
    int j2 = j + 2; j2 = (j2 < r1) ? j2 : r0;
    int j3 = j + 3; j3 = (j3 < r1) ? j3 : r0;
    unsigned o2 = (unsigned)csr_src[j2] * 780u;
    unsigned o3 = (unsigned)csr_src[j3] * 780u;
    unsigned int uC0 = *(const unsigned int*)(xlu + o2 + c0);
    unsigned int uC1 = hasP1 ? *(const unsigned int*)(xlu + o2 + c1) : 0u;
    unsigned int uD0 = *(const unsigned int*)(xlu + o3 + c0);
    unsigned int uD1 = hasP1 ? *(const unsigned int*)(xlu + o3 + c1) : 0u;
    GAT_EDGE(uA0, uA1);
    GAT_EDGE(uB0, uB1);
    uA0 = uC0; uA1 = uC1;
    uB0 = uD0; uB1 = uD1;
  }
  if ((r1 - r0) & 1) GAT_EDGE(uA0, uA1);

  float inv = 1.f / denom;
  __hip_bfloat16* orow = h1out + (size_t)dst * KPAD;
  orow[c0] = __float2bfloat16(fmaxf(acc0a * inv + b_gat[c0], 0.f));
  orow[c0 + 1] = __float2bfloat16(fmaxf(acc0b * inv + b_gat[c0 + 1], 0.f));
  if (hasP1) {
    orow[c1] = __float2bfloat16(fmaxf(acc1a * inv + b_gat[c1], 0.f));
    orow[c1 + 1] = __float2bfloat16(fmaxf(acc1b * inv + b_gat[c1 + 1], 0.f));
  }
  if (t < KPAD - F) orow[F + t] = __float2bfloat16(0.f);
}

// ---------------- GCN aggregation, pair-wise edge loop, bf16 in/out (R11-proven) ----
#define AGG_EDGE(U0, U1, NV)                                                   \
  { float nrm = di * (NV);                                                     \
    float x0a, x0b, x1a, x1b;                                                  \
    bf2unpack(U0, x0a, x0b);                                                   \
    bf2unpack(U1, x1a, x1b);                                                   \
    a0a += nrm * x0a;                                                          \
    a0b += nrm * x0b;                                                          \
    a1a += nrm * x1a;                                                          \
    a1b += nrm * x1b; }

__global__ __launch_bounds__(320) void gcn_agg_k(const __hip_bfloat16* __restrict__ hmat,
                                                 const float* __restrict__ bias,
                                                 const int* __restrict__ row_start,
                                                 const int* __restrict__ csr_src,
                                                 const float* __restrict__ dinv,
                                                 __hip_bfloat16* __restrict__ out) {
  int dst = blockIdx.x;
  int t = threadIdx.x;
  bool hasP1 = (t < 70);
  int c0 = 2 * t;
  int c1 = 640 + 2 * t;
  int r0 = row_start[dst], r1 = row_start[dst + 1];
  float di = dinv[dst];
  float a0a = 0.f, a0b = 0.f, a1a = 0.f, a1b = 0.f;
  const unsigned short* hu = (const unsigned short*)hmat;

  unsigned int uA0, uA1, uB0, uB1;
  float nvA, nvB;
  {
    int sA = csr_src[r0];
    nvA = dinv[sA];
    unsigned oA = (unsigned)sA * 780u;
    uA0 = *(const unsigned int*)(hu + oA + c0);
    uA1 = hasP1 ? *(const unsigned int*)(hu + oA + c1) : 0u;
    int jB = (r0 + 1 < r1) ? r0 + 1 : r0;
    int sB = csr_src[jB];
    nvB = dinv[sB];
    unsigned oB = (unsigned)sB * 780u;
    uB0 = *(const unsigned int*)(hu + oB + c0);
    uB1 = hasP1 ? *(const unsigned int*)(hu + oB + c1) : 0u;
  }
  int j = r0;
#pragma unroll 2
  for (; j + 1 < r1; j += 2) {
    int j2 = j + 2; j2 = (j2 < r1) ? j2 : r0;
    int j3 = j + 3; j3 = (j3 < r1) ? j3 : r0;
    int s2 = csr_src[j2];
    int s3 = csr_src[j3];
    float nv2 = dinv[s2];
    float nv3 = dinv[s3];
    unsigned o2 = (unsigned)s2 * 780u;
    unsigned o3 = (unsigned)s3 * 780u;
    unsigned int uC0 = *(const unsigned int*)(hu + o2 + c0);
    unsigned int uC1 = hasP1 ? *(const unsigned int*)(hu + o2 + c1) : 0u;
    unsigned int uD0 = *(const unsigned int*)(hu + o3 + c0);
    unsigned int uD1 = hasP1 ? *(const unsigned int*)(hu + o3 + c1) : 0u;
    AGG_EDGE(uA0, uA1, nvA);
    AGG_EDGE(uB0, uB1, nvB);
    uA0 = uC0; uA1 = uC1; nvA = nv2;
    uB0 = uD0; uB1 = uD1; nvB = nv3;
  }
  if ((r1 - r0) & 1) AGG_EDGE(uA0, uA1, nvA);

  __hip_bfloat16* o = out + (size_t)dst * F;
  o[c0] = __float2bfloat16(fmaxf(a0a + bias[c0], 0.f));
  o[c0 + 1] = __float2bfloat16(fmaxf(a0b + bias[c0 + 1], 0.f));
  if (hasP1) {
    o[c1] = __float2bfloat16(fmaxf(a1a + bias[c1], 0.f));
    o[c1 + 1] = __float2bfloat16(fmaxf(a1b + bias[c1 + 1], 0.f));
  }
}

// ---------------- pooling: bf16 in; per-graph max & mean; bf16 pooled [NGRAPH x K2PAD] ----
__global__ __launch_bounds__(320) void pool_k(const __hip_bfloat16* __restrict__ hmat,
                                              const int* __restrict__ batch,
                                              __hip_bfloat16* __restrict__ pooled, int Nn) {
  int g = blockIdx.x;
  int t = threadIdx.x;
  __shared__ int lo_s, hi_s;
  if (t == 0) {
    int lo = 0, hi = Nn;
    while (lo < hi) { int mid = (lo + hi) >> 1; if (batch[mid] < g) lo = mid + 1; else hi = mid; }
    lo_s = lo;
    int lo2 = lo, hi2 = Nn;
    while (lo2 < hi2) { int mid = (lo2 + hi2) >> 1; if (batch[mid] < g + 1) lo2 = mid + 1; else hi2 = mid; }
    hi_s = lo2;
  }
  __syncthreads();
  int lo = lo_s, hi = hi_s, cnt = hi - lo;
  bool hasP1 = (t < 70);
  int c0 = 2 * t;
  int c1 = 640 + 2 * t;
  float m0a = -1e30f, m0b = -1e30f, m1a = -1e30f, m1b = -1e30f;
  float s0a = 0.f, s0b = 0.f, s1a = 0.f, s1b = 0.f;
  const unsigned short* hu = (const unsigned short*)hmat;
  for (int n = lo; n < hi; ++n) {
    const unsigned short* hp = hu + (size_t)n * F;
    unsigned int u0 = *(const unsigned int*)(hp + c0);
    float v0x, v0y;
    bf2unpack(u0, v0x, v0y);
    m0a = fmaxf(m0a, v0x); s0a += v0x;
    m0b = fmaxf(m0b, v0y); s0b += v0y;
    if (hasP1) {
      unsigned int u1 = *(const unsigned int*)(hp + c1);
      float v1x, v1y;
      bf2unpack(u1, v1x, v1y);
      m1a = fmaxf(m1a, v1x); s1a += v1x;
      m1b = fmaxf(m1b, v1y); s1b += v1y;
    }
  }
  float inv = 1.f / (float)(cnt > 0 ? cnt : 1);
  __hip_bfloat16* o = pooled + (size_t)g * K2PAD;
  o[c0] = __float2bfloat16(cnt ? m0a : 0.f);
  o[c0 + 1] = __float2bfloat16(cnt ? m0b : 0.f);
  o[780 + c0] = __float2bfloat16(s0a * inv);
  o[780 + c0 + 1] = __float2bfloat16(s0b * inv);
  if (hasP1) {
    o[c1] = __float2bfloat16(cnt ? m1a : 0.f);
    o[c1 + 1] = __float2bfloat16(cnt ? m1b : 0.f);
    o[780 + c1] = __float2bfloat16(s1a * inv);
    o[780 + c1 + 1] = __float2bfloat16(s1b * inv);
  }
  if (t < K2PAD - 1560) o[1560 + t] = __float2bfloat16(0.f);
}

// ---------------- launcher ----------------
extern "C" void kernel_launch(void* const* d_in, const int* in_sizes, int n_in,
                              void* d_out, int out_size, void* d_ws, size_t ws_size,
                              hipStream_t stream) {
  const float* x     = (const float*)d_in[0];
  const int*   ei    = (const int*)d_in[1];
  const int*   batch = (const int*)d_in[2];
  const float* Wl    = (const float*)d_in[3];
  const float* Wr    = (const float*)d_in[4];
  const float* att   = (const float*)d_in[5];
  const float* b_gat = (const float*)d_in[6];
  const float* W_gcn = (const float*)d_in[7];
  const float* b_gcn = (const float*)d_in[8];
  const float* W_fc1 = (const float*)d_in[9];
  const float* b_fc1 = (const float*)d_in[10];
  const float* W_fc2 = (const float*)d_in[11];
  const float* b_fc2 = (const float*)d_in[12];
  float* out = (float*)d_out;

  int Nn = in_sizes[0] / 78;   // 16384
  int E  = in_sizes[1] / 2;    // 262144
  int EP = E + Nn;             // with self-loops
  const int* srcv = ei;
  const int* dstv = ei + E;

  // workspace layout
  char* wsb = (char*)d_ws;
  size_t NB = (size_t)Nn * F;
  __hip_bfloat16* xrb = (__hip_bfloat16*)wsb;                 // [Nn*F] bf16: xr; later aggbf
  __hip_bfloat16* aggbf = xrb;                                // alias (xr dead by then)
  wsb += NB * sizeof(__hip_bfloat16);
  __hip_bfloat16* bufBF = (__hip_bfloat16*)wsb;               // [Nn*F] bf16: xl, then h2
  wsb += NB * sizeof(__hip_bfloat16);
  __hip_bfloat16* h1bf = (__hip_bfloat16*)wsb;                // [Nn*KPAD] bf16: GAT out
  wsb += (size_t)Nn * KPAD * sizeof(__hip_bfloat16);
  __hip_bfloat16* xbf = (__hip_bfloat16*)wsb;                 // [Nn*K1] bf16
  wsb += (size_t)Nn * K1 * sizeof(__hip_bfloat16);
  __hip_bfloat16* Wlrb = (__hip_bfloat16*)wsb;                // [N1PAD*K1]
  wsb += (size_t)N1PAD * K1 * sizeof(__hip_bfloat16);
  __hip_bfloat16* Wtb = (__hip_bfloat16*)wsb;                 // [NPAD*KPAD]
  wsb += (size_t)NPAD * KPAD * sizeof(__hip_bfloat16);
  __hip_bfloat16* Wfc1b = (__hip_bfloat16*)wsb;               // [N2PAD*K2PAD]
  wsb += (size_t)N2PAD * K2PAD * sizeof(__hip_bfloat16);
  __hip_bfloat16* Wfc2b = (__hip_bfloat16*)wsb;               // [128*N2PAD]
  wsb += (size_t)128 * N2PAD * sizeof(__hip_bfloat16);
  __hip_bfloat16* pooledb = (__hip_bfloat16*)wsb;             // [NGRAPH*K2PAD]
  wsb += (size_t)NGRAPH * K2PAD * sizeof(__hip_bfloat16);
  __hip_bfloat16* g1b = (__hip_bfloat16*)wsb;                 // [NGRAPH*N2PAD] FC1 out
  wsb += (size_t)NGRAPH * N2PAD * sizeof(__hip_bfloat16);
  int* csr_src = (int*)wsb;      wsb += (size_t)EP * sizeof(int);
  int* counts = (int*)wsb;       wsb += (size_t)Nn * sizeof(int);
  int* row_start = (int*)wsb;    wsb += (size_t)(Nn + 1) * sizeof(int);
  int* cursor = (int*)wsb;       wsb += (size_t)Nn * sizeof(int);
  float* dinv = (float*)wsb;     wsb += (size_t)Nn * sizeof(float);
  size_t need = (size_t)(wsb - (char*)d_ws);
  if (need > ws_size) {
    fprintf(stderr, "kernel_launch: ws too small: need %zu have %zu\n", need, ws_size);
  }

  dim3 blk(256);

  // merged preprocessing: all casts + out=bias + counts=1
  int prep_total = Nn * K1 + N1PAD * K1 + NPAD * KPAD + N2PAD * K2PAD + 128 * N2PAD
                 + NGRAPH * 128 + Nn;
  prep_k<<<(prep_total + 255) / 256, 256, 0, stream>>>(x, Wl, Wr, W_gcn, W_fc1, W_fc2, b_fc2,
                                                       xbf, Wlrb, Wtb, Wfc1b, Wfc2b,
                                                       out, counts, Nn);

  // CSR by dst (self-loop slot first)
  count_k<<<512, 256, 0, stream>>>(dstv, E, counts);
  scan_k<<<1, 256, 0, stream>>>(counts, row_start, cursor, csr_src, dinv, Nn);
  scatter_k<<<512, 256, 0, stream>>>(srcv, dstv, E, cursor, csr_src);

  // transform GEMM (bf16 MFMA, BK=64): xbf @ Wlrb^T -> xl (bufBF) | xr (xrb), both bf16
  dim3 g1grid(N1PAD / 128, Nn / 128);
  gemm_bf16_dual_k<<<g1grid, blk, 0, stream>>>((const unsigned short*)xbf,
                                               (const unsigned short*)Wlrb,
                                               bufBF, xrb, Nn, N1, K1, K1);

  // GATv2 fused single-pass -> h1bf (bf16, KPAD stride, padded cols zeroed)
  gatv2_fused_k<<<Nn, 320, 0, stream>>>(bufBF, xrb, att, b_gat, row_start, csr_src, h1bf);

  // GCN matmul (bf16 MFMA, BK=64): h1bf @ Wtb^T -> h2 bf16 (bufBF, xl dead)
  dim3 g2grid(NPAD / 128, Nn / 128);
  gemm_bf16_obf_k<<<g2grid, blk, 0, stream>>>((const unsigned short*)h1bf,
                                              (const unsigned short*)Wtb,
                                              bufBF, Nn, F, KPAD, KPAD);

  // normalized aggregation (bf16 gather) -> bf16 aggbf (aliases dead xr)
  gcn_agg_k<<<Nn, 320, 0, stream>>>(bufBF, b_gcn, row_start, csr_src, dinv, aggbf);

  // pooling (bf16 in) -> bf16 pooled [NGRAPH x K2PAD], zero-padded
  pool_k<<<NGRAPH, 320, 0, stream>>>(aggbf, batch, pooledb, Nn);

  // FC1 (bf16 MFMA, BK=64): g1b = relu(pooled @ Wfc1b^T + b_fc1), bf16, padded to N2PAD
  dim3 fc1grid(N2PAD / 128, NGRAPH / 128);
  gemm_bf16_fc1_k<<<fc1grid, blk, 0, stream>>>((const unsigned short*)pooledb,
                                               (const unsigned short*)Wfc1b,
                                               b_fc1, g1b, NGRAPH, 1500, K2PAD, K2PAD);

  // FC2 (bf16 MFMA split-K): out += g1b @ Wfc2b^T (out pre-inited with b_fc2)
  dim3 fc2grid(1, NGRAPH / 128, 6);   // kchunk 256 -> 4 BK iters per block
  gemm_bf16_fc2_k<<<fc2grid, blk, 0, stream>>>((const unsigned short*)g1b,
                                               (const unsigned short*)Wfc2b,
                                               out, NGRAPH, 256);
}

// Round 15
// 497.538 us; speedup vs baseline: 1.0749x; 1.0603x over previous
//
#include <hip/hip_runtime.h>
#include <hip/hip_bf16.h>
#include <math.h>
#include <stdio.h>

#define HEADS 10
#define CH 78
#define F 780          // HEADS*CH
#define NGRAPH 512
#define NEG 0.2f
#define KPAD 832       // GCN GEMM K: 780 padded to mult of 64
#define NPAD 896       // GCN GEMM N: 780 padded to mult of 128
#define K1 128         // transform GEMM K: 78 padded to mult of 64
#define N1 1560        // transform GEMM N: 780 (xl) + 780 (xr)
#define N1PAD 1664     // 1560 padded to mult of 128
#define K2PAD 1600     // FC1 K: 1560 padded to mult of 64
#define N2PAD 1536     // FC1 N: 1500 padded to mult of 128 (also FC2 K with zero pad)

typedef __attribute__((ext_vector_type(8))) short short8;
typedef __attribute__((ext_vector_type(4))) float f32x4;

__device__ inline void bf2unpack(unsigned int u, float& lo, float& hi) {
  union { unsigned int ui; float f; } a, b;
  a.ui = u << 16;
  b.ui = u & 0xffff0000u;
  lo = a.f; hi = b.f;
}

// ---------------- merged preprocessing: casts + counts init + out init ----------
__global__ __launch_bounds__(256) void prep_k(const float* __restrict__ x,
                                              const float* __restrict__ Wl,
                                              const float* __restrict__ Wr,
                                              const float* __restrict__ Wgcn,
                                              const float* __restrict__ Wfc1,
                                              const float* __restrict__ Wfc2,
                                              const float* __restrict__ bfc2,
                                              __hip_bfloat16* __restrict__ xb,
                                              __hip_bfloat16* __restrict__ Wlrb,
                                              __hip_bfloat16* __restrict__ Wtb,
                                              __hip_bfloat16* __restrict__ Wfc1b,
                                              __hip_bfloat16* __restrict__ Wfc2b,
                                              float* __restrict__ outinit,
                                              int* __restrict__ counts, int Nn) {
  int i = blockIdx.x * 256 + threadIdx.x;
  int s0 = Nn * K1;
  int s1 = s0 + N1PAD * K1;
  int s2 = s1 + NPAD * KPAD;
  int s3 = s2 + N2PAD * K2PAD;
  int s4 = s3 + 128 * N2PAD;
  int s5 = s4 + NGRAPH * 128;
  int s6 = s5 + Nn;
  if (i < s0) {
    int row = i / K1, k = i - row * K1;
    xb[i] = __float2bfloat16((k < 78) ? x[(size_t)row * 78 + k] : 0.f);
  } else if (i < s1) {
    int j = i - s0;
    int n = j / K1, k = j - n * K1;
    float v = 0.f;
    if (k < 78 && n < N1) v = (n < F) ? Wl[(size_t)k * F + n] : Wr[(size_t)k * F + (n - F)];
    Wlrb[j] = __float2bfloat16(v);
  } else if (i < s2) {
    int j = i - s1;
    int n = j / KPAD, k = j - n * KPAD;
    float v = (n < F && k < F) ? Wgcn[(size_t)k * F + n] : 0.f;
    Wtb[j] = __float2bfloat16(v);
  } else if (i < s3) {
    int j = i - s2;
    int n = j / K2PAD, k = j - n * K2PAD;
    float v = (n < 1500 && k < 1560) ? Wfc1[(size_t)k * 1500 + n] : 0.f;
    Wfc1b[j] = __float2bfloat16(v);
  } else if (i < s4) {
    int j = i - s3;
    int n = j / N2PAD, k = j - n * N2PAD;     // n: out col 0..127, k: 0..1535
    float v = (k < 1500) ? Wfc2[(size_t)k * 128 + n] : 0.f;
    Wfc2b[j] = __float2bfloat16(v);
  } else if (i < s5) {
    int j = i - s4;
    outinit[j] = bfc2[j & 127];
  } else if (i < s6) {
    counts[i - s5] = 1;   // self-loop
  }
}

// ---------------- bf16 MFMA GEMM core, BK=64 ----------------
__device__ inline void gl_lds16(const unsigned short* g, unsigned short* l) {
  __builtin_amdgcn_global_load_lds(
      (const __attribute__((address_space(1))) unsigned int*)g,
      (__attribute__((address_space(3))) unsigned int*)l, 16, 0, 0);
}

// A: [M][lda] bf16 row-major, Bt: [Ncols_pad][lda] bf16 (B transposed). K mult of 64.
// 128x128 tile, 4 waves x (4x4) mfma_f32_16x16x32_bf16.
#define MFMA_CORE64(A, Bt, lda, K)                                                \
  __shared__ unsigned short As[128 * 64];                                         \
  __shared__ unsigned short Bs[128 * 64];                                         \
  int tid = threadIdx.x;                                                          \
  int wave = tid >> 6, lane = tid & 63;                                           \
  int m0 = blockIdx.y * 128, n0 = blockIdx.x * 128;                               \
  int wr = (wave >> 1) * 64, wc = (wave & 1) * 64;                                \
  f32x4 acc[4][4];                                                                \
  _Pragma("unroll")                                                               \
  for (int i = 0; i < 4; ++i)                                                     \
    _Pragma("unroll")                                                             \
    for (int j = 0; j < 4; ++j) acc[i][j] = (f32x4){0.f, 0.f, 0.f, 0.f};          \
  int lrow = lane >> 3;                                                           \
  int lcol = (lane & 7) * 8;                                                      \
  const unsigned short* gA0 = A + (size_t)(m0 + wave * 32 + lrow) * lda + lcol;   \
  const unsigned short* gB0 = Bt + (size_t)(n0 + wave * 32 + lrow) * lda + lcol;  \
  unsigned short* lA = As + (wave * 32) * 64;                                     \
  unsigned short* lB = Bs + (wave * 32) * 64;                                     \
  int q8 = (lane >> 4) * 8;                                                       \
  int fr = lane & 15;                                                             \
  for (int k0 = 0; k0 < K; k0 += 64) {                                            \
    _Pragma("unroll")                                                             \
    for (int c = 0; c < 4; ++c) {                                                 \
      gl_lds16(gA0 + (size_t)(8 * c) * lda, lA + (8 * c) * 64);                   \
      gl_lds16(gB0 + (size_t)(8 * c) * lda, lB + (8 * c) * 64);                   \
    }                                                                             \
    gA0 += 64; gB0 += 64;                                                         \
    __syncthreads();                                                              \
    _Pragma("unroll")                                                             \
    for (int ks = 0; ks < 64; ks += 32) {                                         \
      short8 a[4], b[4];                                                          \
      _Pragma("unroll")                                                           \
      for (int i = 0; i < 4; ++i) a[i] = *(const short8*)&As[(wr + 16 * i + fr) * 64 + ks + q8]; \
      _Pragma("unroll")                                                           \
      for (int j = 0; j < 4; ++j) b[j] = *(const short8*)&Bs[(wc + 16 * j + fr) * 64 + ks + q8]; \
      _Pragma("unroll")                                                           \
      for (int i = 0; i < 4; ++i)                                                 \
        _Pragma("unroll")                                                         \
        for (int j = 0; j < 4; ++j)                                               \
          acc[i][j] = __builtin_amdgcn_mfma_f32_16x16x32_bf16(a[i], b[j], acc[i][j], 0, 0, 0); \
    }                                                                             \
    __syncthreads();                                                              \
  }                                                                               \
  int cq = (lane >> 4) * 4;

// variant 1: dual bf16 output (cols < F -> Cl stride F; cols >= F -> Cr stride F)
__global__ __launch_bounds__(256) void gemm_bf16_dual_k(const unsigned short* __restrict__ A,
                                                        const unsigned short* __restrict__ Bt,
                                                        __hip_bfloat16* __restrict__ Cl,
                                                        __hip_bfloat16* __restrict__ Cr,
                                                        int M, int Ncols, int K, int lda) {
  MFMA_CORE64(A, Bt, lda, K)
#pragma unroll
  for (int i = 0; i < 4; ++i) {
#pragma unroll
    for (int j = 0; j < 4; ++j) {
      int col = n0 + wc + 16 * j + fr;
      if (col >= Ncols) continue;
      int rowb = m0 + wr + 16 * i + cq;
#pragma unroll
      for (int r = 0; r < 4; ++r) {
        int row = rowb + r;
        if (row >= M) continue;
        float v = acc[i][j][r];
        if (col < F) Cl[(size_t)row * F + col] = __float2bfloat16(v);
        else         Cr[(size_t)row * F + (col - F)] = __float2bfloat16(v);
      }
    }
  }
}

// variant 2: bf16 output, row stride Ncols
__global__ __launch_bounds__(256) void gemm_bf16_obf_k(const unsigned short* __restrict__ A,
                                                       const unsigned short* __restrict__ Bt,
                                                       __hip_bfloat16* __restrict__ C,
                                                       int M, int Ncols, int K, int lda) {
  MFMA_CORE64(A, Bt, lda, K)
#pragma unroll
  for (int i = 0; i < 4; ++i) {
#pragma unroll
    for (int j = 0; j < 4; ++j) {
      int col = n0 + wc + 16 * j + fr;
      if (col >= Ncols) continue;
      int rowb = m0 + wr + 16 * i + cq;
#pragma unroll
      for (int r = 0; r < 4; ++r) {
        int row = rowb + r;
        if (row < M) C[(size_t)row * Ncols + col] = __float2bfloat16(acc[i][j][r]);
      }
    }
  }
}

// variant 3 (FC1): bias+relu epilogue, bf16 output stride N2PAD, zero pad cols >= Nreal
__global__ __launch_bounds__(256) void gemm_bf16_fc1_k(const unsigned short* __restrict__ A,
                                                       const unsigned short* __restrict__ Bt,
                                                       const float* __restrict__ bias,
                                                       __hip_bfloat16* __restrict__ C,
                                                       int M, int Nreal, int K, int lda) {
  MFMA_CORE64(A, Bt, lda, K)
#pragma unroll
  for (int i = 0; i < 4; ++i) {
#pragma unroll
    for (int j = 0; j < 4; ++j) {
      int col = n0 + wc + 16 * j + fr;
      int rowb = m0 + wr + 16 * i + cq;
#pragma unroll
      for (int r = 0; r < 4; ++r) {
        int row = rowb + r;
        if (row >= M) continue;
        float v = 0.f;
        if (col < Nreal) v = fmaxf(acc[i][j][r] + bias[col], 0.f);
        C[(size_t)row * N2PAD + col] = __float2bfloat16(v);
      }
    }
  }
}

// variant 4 (FC2): split-K over blockIdx.z, f32 atomicAdd into pre-initialized C [M x 128]
__global__ __launch_bounds__(256) void gemm_bf16_fc2_k(const unsigned short* __restrict__ A,
                                                       const unsigned short* __restrict__ Bt,
                                                       float* C, int M, int kchunk) {
  const unsigned short* A2 = A + (size_t)blockIdx.z * kchunk;
  const unsigned short* B2 = Bt + (size_t)blockIdx.z * kchunk;
  MFMA_CORE64(A2, B2, N2PAD, kchunk)
#pragma unroll
  for (int i = 0; i < 4; ++i) {
#pragma unroll
    for (int j = 0; j < 4; ++j) {
      int col = n0 + wc + 16 * j + fr;   // n0 == 0, col < 128
      int rowb = m0 + wr + 16 * i + cq;
#pragma unroll
      for (int r = 0; r < 4; ++r) {
        int row = rowb + r;
        if (row < M && col < 128) atomicAdd(&C[(size_t)row * 128 + col], acc[i][j][r]);
      }
    }
  }
}

// ---------------- CSR build (by dst, self-loop first per node) ----------------
__global__ void count_k(const int* __restrict__ dstv, int E, int* counts) {
  for (int e = blockIdx.x * blockDim.x + threadIdx.x; e < E; e += gridDim.x * blockDim.x)
    atomicAdd(&counts[dstv[e]], 1);
}
__global__ __launch_bounds__(256) void scan_k(const int* __restrict__ counts,
                                              int* __restrict__ row_start, int Nn) {
  __shared__ int part[256];
  int t = threadIdx.x;
  int chunk = (Nn + 255) / 256;
  int b0 = t * chunk, b1 = min(b0 + chunk, Nn);
  int s = 0;
  for (int i = b0; i < b1; ++i) s += counts[i];
  part[t] = s;
  __syncthreads();
  // Hillis-Steele inclusive scan over 256 partials
  for (int off = 1; off < 256; off <<= 1) {
    int u = (t >= off) ? part[t - off] : 0;
    __syncthreads();
    part[t] += u;
    __syncthreads();
  }
  int run = part[t] - s;   // exclusive prefix for this thread's chunk
  for (int i = b0; i < b1; ++i) { row_start[i] = run; run += counts[i]; }
  if (t == 255) row_start[Nn] = run;
}
// merged: self-loop slot + cursor init + dinv (parallel across 64 blocks)
__global__ void node_init_k(const int* __restrict__ row_start, int* cursor, int* csr_src,
                            float* dinv, int Nn) {
  int i = blockIdx.x * blockDim.x + threadIdx.x;
  if (i < Nn) {
    int p = row_start[i];
    csr_src[p] = i;
    cursor[i] = p + 1;
    dinv[i] = rsqrtf((float)(row_start[i + 1] - p));
  }
}
__global__ void scatter_k(const int* __restrict__ srcv, const int* __restrict__ dstv, int E,
                          int* cursor, int* csr_src) {
  for (int e = blockIdx.x * blockDim.x + threadIdx.x; e < E; e += gridDim.x * blockDim.x) {
    int pos = atomicAdd(&cursor[dstv[e]], 1);
    csr_src[pos] = srcv[e];
  }
}

// ---------------- GATv2 fused single-pass, bf16, pair-wise edge loop (R11-proven) ----
// per-dst block, 320 thr = 10 heads x 32 lanes; ushort2 gathers; xr in bf16.
#define GAT_EDGE(U0, U1)                                                       \
  { float x0a, x0b, x1a, x1b;                                                  \
    bf2unpack(U0, x0a, x0b);                                                   \
    bf2unpack(U1, x1a, x1b);                                                   \
    float v, lv;                                                               \
    v = x0a + xr0a; lv = fmaxf(v, NEG * v); float p = at0a * lv;               \
    v = x0b + xr0b; lv = fmaxf(v, NEG * v); p += at0b * lv;                    \
    v = x1a + xr1a; lv = fmaxf(v, NEG * v); p += at1a * lv;                    \
    v = x1b + xr1b; lv = fmaxf(v, NEG * v); p += at1b * lv;                    \
    p += __shfl_xor(p, 16, 32);                                                \
    p += __shfl_xor(p, 8, 32);                                                 \
    p += __shfl_xor(p, 4, 32);                                                 \
    p += __shfl_xor(p, 2, 32);                                                 \
    p += __shfl_xor(p, 1, 32);                                                 \
    p = __expf(p);                                                             \
    denom += p;                                                                \
    acc0a += p * x0a;                                                          \
    acc0b += p * x0b;                                                          \
    acc1a += p * x1a;                                                          \
    acc1b += p * x1b; }

__global__ __launch_bounds__(320) void gatv2_fused_k(const __hip_bfloat16* __restrict__ xl,
                                                     const __hip_bfloat16* __restrict__ xr,
                                                     const float* __restrict__ att,
                                                     const float* __restrict__ b_gat,
                                                     const int* __restrict__ row_start,
                                                     const int* __restrict__ csr_src,
                                                     __hip_bfloat16* __restrict__ h1out) {
  int dst = blockIdx.x;
  int t = threadIdx.x;
  int h = t >> 5, w = t & 31;
  int hb = h * CH;
  bool hasP1 = (w < 7);
  int c0 = hb + 2 * w;
  int c1 = hb + 64 + 2 * w;
  const unsigned short* xru = (const unsigned short*)xr + (size_t)dst * F;
  float xr0a, xr0b, xr1a, xr1b;
  bf2unpack(*(const unsigned int*)(xru + c0), xr0a, xr0b);
  {
    unsigned int u = hasP1 ? *(const unsigned int*)(xru + c1) : 0u;
    bf2unpack(u, xr1a, xr1b);
  }
  float at0a = att[c0], at0b = att[c0 + 1];
  float at1a = hasP1 ? att[c1] : 0.f, at1b = hasP1 ? att[c1 + 1] : 0.f;
  int r0 = row_start[dst], r1 = row_start[dst + 1];
  float acc0a = 0.f, acc0b = 0.f, acc1a = 0.f, acc1b = 0.f, denom = 0.f;
  const unsigned short* xlu = (const unsigned short*)xl;

  // stage A = edge j, stage B = edge j+1 (wrap to r0; deg >= 1 via self-loop)
  unsigned int uA0, uA1, uB0, uB1;
  {
    unsigned oA = (unsigned)csr_src[r0] * 780u;
    uA0 = *(const unsigned int*)(xlu + oA + c0);
    uA1 = hasP1 ? *(const unsigned int*)(xlu + oA + c1) : 0u;
    int jB = (r0 + 1 < r1) ? r0 + 1 : r0;
    unsigned oB = (unsigned)csr_src[jB] * 780u;
    uB0 = *(const unsigned int*)(xlu + oB + c0);
    uB1 = hasP1 ? *(const unsigned int*)(xlu + oB + c1) : 0u;
  }
  int j = r0;
#pragma unroll 2
  for (; j + 1 < r1; j += 2) {
    int j2 = j + 2; j2 = (j2 < r1) ? j2 : r0;
    int j3 = j + 3; j3 = (j3 < r1) ? j3 : r0;
    unsigned o2 = (unsigned)csr_src[j2] * 780u;
    unsigned o3 = (unsigned)csr_src[j3] * 780u;
    unsigned int uC0 = *(const unsigned int*)(xlu + o2 + c0);
    unsigned int uC1 = hasP1 ? *(const unsigned int*)(xlu + o2 + c1) : 0u;
    unsigned int uD0 = *(const unsigned int*)(xlu + o3 + c0);
    unsigned int uD1 = hasP1 ? *(const unsigned int*)(xlu + o3 + c1) : 0u;
    GAT_EDGE(uA0, uA1);
    GAT_EDGE(uB0, uB1);
    uA0 = uC0; uA1 = uC1;
    uB0 = uD0; uB1 = uD1;
  }
  if ((r1 - r0) & 1) GAT_EDGE(uA0, uA1);

  float inv = 1.f / denom;
  __hip_bfloat16* orow = h1out + (size_t)dst * KPAD;
  orow[c0] = __float2bfloat16(fmaxf(acc0a * inv + b_gat[c0], 0.f));
  orow[c0 + 1] = __float2bfloat16(fmaxf(acc0b * inv + b_gat[c0 + 1], 0.f));
  if (hasP1) {
    orow[c1] = __float2bfloat16(fmaxf(acc1a * inv + b_gat[c1], 0.f));
    orow[c1 + 1] = __float2bfloat16(fmaxf(acc1b * inv + b_gat[c1 + 1], 0.f));
  }
  if (t < KPAD - F) orow[F + t] = __float2bfloat16(0.f);
}

// ---------------- GCN aggregation, pair-wise edge loop, bf16 in/out (R11-proven) ----
#define AGG_EDGE(U0, U1, NV)                                                   \
  { float nrm = di * (NV);                                                     \
    float x0a, x0b, x1a, x1b;                                                  \
    bf2unpack(U0, x0a, x0b);                                                   \
    bf2unpack(U1, x1a, x1b);                                                   \
    a0a += nrm * x0a;                                                          \
    a0b += nrm * x0b;                                                          \
    a1a += nrm * x1a;                                                          \
    a1b += nrm * x1b; }

__global__ __launch_bounds__(320) void gcn_agg_k(const __hip_bfloat16* __restrict__ hmat,
                                                 const float* __restrict__ bias,
                                                 const int* __restrict__ row_start,
                                                 const int* __restrict__ csr_src,
                                                 const float* __restrict__ dinv,
                                                 __hip_bfloat16* __restrict__ out) {
  int dst = blockIdx.x;
  int t = threadIdx.x;
  bool hasP1 = (t < 70);
  int c0 = 2 * t;
  int c1 = 640 + 2 * t;
  int r0 = row_start[dst], r1 = row_start[dst + 1];
  float di = dinv[dst];
  float a0a = 0.f, a0b = 0.f, a1a = 0.f, a1b = 0.f;
  const unsigned short* hu = (const unsigned short*)hmat;

  unsigned int uA0, uA1, uB0, uB1;
  float nvA, nvB;
  {
    int sA = csr_src[r0];
    nvA = dinv[sA];
    unsigned oA = (unsigned)sA * 780u;
    uA0 = *(const unsigned int*)(hu + oA + c0);
    uA1 = hasP1 ? *(const unsigned int*)(hu + oA + c1) : 0u;
    int jB = (r0 + 1 < r1) ? r0 + 1 : r0;
    int sB = csr_src[jB];
    nvB = dinv[sB];
    unsigned oB = (unsigned)sB * 780u;
    uB0 = *(const unsigned int*)(hu + oB + c0);
    uB1 = hasP1 ? *(const unsigned int*)(hu + oB + c1) : 0u;
  }
  int j = r0;
#pragma unroll 2
  for (; j + 1 < r1; j += 2) {
    int j2 = j + 2; j2 = (j2 < r1) ? j2 : r0;
    int j3 = j + 3; j3 = (j3 < r1) ? j3 : r0;
    int s2 = csr_src[j2];
    int s3 = csr_src[j3];
    float nv2 = dinv[s2];
    float nv3 = dinv[s3];
    unsigned o2 = (unsigned)s2 * 780u;
    unsigned o3 = (unsigned)s3 * 780u;
    unsigned int uC0 = *(const unsigned int*)(hu + o2 + c0);
    unsigned int uC1 = hasP1 ? *(const unsigned int*)(hu + o2 + c1) : 0u;
    unsigned int uD0 = *(const unsigned int*)(hu + o3 + c0);
    unsigned int uD1 = hasP1 ? *(const unsigned int*)(hu + o3 + c1) : 0u;
    AGG_EDGE(uA0, uA1, nvA);
    AGG_EDGE(uB0, uB1, nvB);
    uA0 = uC0; uA1 = uC1; nvA = nv2;
    uB0 = uD0; uB1 = uD1; nvB = nv3;
  }
  if ((r1 - r0) & 1) AGG_EDGE(uA0, uA1, nvA);

  __hip_bfloat16* o = out + (size_t)dst * F;
  o[c0] = __float2bfloat16(fmaxf(a0a + bias[c0], 0.f));
  o[c0 + 1] = __float2bfloat16(fmaxf(a0b + bias[c0 + 1], 0.f));
  if (hasP1) {
    o[c1] = __float2bfloat16(fmaxf(a1a + bias[c1], 0.f));
    o[c1 + 1] = __float2bfloat16(fmaxf(a1b + bias[c1 + 1], 0.f));
  }
}

// ---------------- pooling: bf16 in; per-graph max & mean; bf16 pooled [NGRAPH x K2PAD] ----
__global__ __launch_bounds__(320) void pool_k(const __hip_bfloat16* __restrict__ hmat,
                                              const int* __restrict__ batch,
                                              __hip_bfloat16* __restrict__ pooled, int Nn) {
  int g = blockIdx.x;
  int t = threadIdx.x;
  __shared__ int lo_s, hi_s;
  if (t == 0) {
    int lo = 0, hi = Nn;
    while (lo < hi) { int mid = (lo + hi) >> 1; if (batch[mid] < g) lo = mid + 1; else hi = mid; }
    lo_s = lo;
    int lo2 = lo, hi2 = Nn;
    while (lo2 < hi2) { int mid = (lo2 + hi2) >> 1; if (batch[mid] < g + 1) lo2 = mid + 1; else hi2 = mid; }
    hi_s = lo2;
  }
  __syncthreads();
  int lo = lo_s, hi = hi_s, cnt = hi - lo;
  bool hasP1 = (t < 70);
  int c0 = 2 * t;
  int c1 = 640 + 2 * t;
  float m0a = -1e30f, m0b = -1e30f, m1a = -1e30f, m1b = -1e30f;
  float s0a = 0.f, s0b = 0.f, s1a = 0.f, s1b = 0.f;
  const unsigned short* hu = (const unsigned short*)hmat;
  for (int n = lo; n < hi; ++n) {
    const unsigned short* hp = hu + (size_t)n * F;
    unsigned int u0 = *(const unsigned int*)(hp + c0);
    float v0x, v0y;
    bf2unpack(u0, v0x, v0y);
    m0a = fmaxf(m0a, v0x); s0a += v0x;
    m0b = fmaxf(m0b, v0y); s0b += v0y;
    if (hasP1) {
      unsigned int u1 = *(const unsigned int*)(hp + c1);
      float v1x, v1y;
      bf2unpack(u1, v1x, v1y);
      m1a = fmaxf(m1a, v1x); s1a += v1x;
      m1b = fmaxf(m1b, v1y); s1b += v1y;
    }
  }
  float inv = 1.f / (float)(cnt > 0 ? cnt : 1);
  __hip_bfloat16* o = pooled + (size_t)g * K2PAD;
  o[c0] = __float2bfloat16(cnt ? m0a : 0.f);
  o[c0 + 1] = __float2bfloat16(cnt ? m0b : 0.f);
  o[780 + c0] = __float2bfloat16(s0a * inv);
  o[780 + c0 + 1] = __float2bfloat16(s0b * inv);
  if (hasP1) {
    o[c1] = __float2bfloat16(cnt ? m1a : 0.f);
    o[c1 + 1] = __float2bfloat16(cnt ? m1b : 0.f);
    o[780 + c1] = __float2bfloat16(s1a * inv);
    o[780 + c1 + 1] = __float2bfloat16(s1b * inv);
  }
  if (t < K2PAD - 1560) o[1560 + t] = __float2bfloat16(0.f);
}

// ---------------- launcher ----------------
extern "C" void kernel_launch(void* const* d_in, const int* in_sizes, int n_in,
                              void* d_out, int out_size, void* d_ws, size_t ws_size,
                              hipStream_t stream) {
  const float* x     = (const float*)d_in[0];
  const int*   ei    = (const int*)d_in[1];
  const int*   batch = (const int*)d_in[2];
  const float* Wl    = (const float*)d_in[3];
  const float* Wr    = (const float*)d_in[4];
  const float* att   = (const float*)d_in[5];
  const float* b_gat = (const float*)d_in[6];
  const float* W_gcn = (const float*)d_in[7];
  const float* b_gcn = (const float*)d_in[8];
  const float* W_fc1 = (const float*)d_in[9];
  const float* b_fc1 = (const float*)d_in[10];
  const float* W_fc2 = (const float*)d_in[11];
  const float* b_fc2 = (const float*)d_in[12];
  float* out = (float*)d_out;

  int Nn = in_sizes[0] / 78;   // 16384
  int E  = in_sizes[1] / 2;    // 262144
  int EP = E + Nn;             // with self-loops
  const int* srcv = ei;
  const int* dstv = ei + E;

  // workspace layout
  char* wsb = (char*)d_ws;
  size_t NB = (size_t)Nn * F;
  __hip_bfloat16* xrb = (__hip_bfloat16*)wsb;                 // [Nn*F] bf16: xr; later aggbf
  __hip_bfloat16* aggbf = xrb;                                // alias (xr dead by then)
  wsb += NB * sizeof(__hip_bfloat16);
  __hip_bfloat16* bufBF = (__hip_bfloat16*)wsb;               // [Nn*F] bf16: xl, then h2
  wsb += NB * sizeof(__hip_bfloat16);
  __hip_bfloat16* h1bf = (__hip_bfloat16*)wsb;                // [Nn*KPAD] bf16: GAT out
  wsb += (size_t)Nn * KPAD * sizeof(__hip_bfloat16);
  __hip_bfloat16* xbf = (__hip_bfloat16*)wsb;                 // [Nn*K1] bf16
  wsb += (size_t)Nn * K1 * sizeof(__hip_bfloat16);
  __hip_bfloat16* Wlrb = (__hip_bfloat16*)wsb;                // [N1PAD*K1]
  wsb += (size_t)N1PAD * K1 * sizeof(__hip_bfloat16);
  __hip_bfloat16* Wtb = (__hip_bfloat16*)wsb;                 // [NPAD*KPAD]
  wsb += (size_t)NPAD * KPAD * sizeof(__hip_bfloat16);
  __hip_bfloat16* Wfc1b = (__hip_bfloat16*)wsb;               // [N2PAD*K2PAD]
  wsb += (size_t)N2PAD * K2PAD * sizeof(__hip_bfloat16);
  __hip_bfloat16* Wfc2b = (__hip_bfloat16*)wsb;               // [128*N2PAD]
  wsb += (size_t)128 * N2PAD * sizeof(__hip_bfloat16);
  __hip_bfloat16* pooledb = (__hip_bfloat16*)wsb;             // [NGRAPH*K2PAD]
  wsb += (size_t)NGRAPH * K2PAD * sizeof(__hip_bfloat16);
  __hip_bfloat16* g1b = (__hip_bfloat16*)wsb;                 // [NGRAPH*N2PAD] FC1 out
  wsb += (size_t)NGRAPH * N2PAD * sizeof(__hip_bfloat16);
  int* csr_src = (int*)wsb;      wsb += (size_t)EP * sizeof(int);
  int* counts = (int*)wsb;       wsb += (size_t)Nn * sizeof(int);
  int* row_start = (int*)wsb;    wsb += (size_t)(Nn + 1) * sizeof(int);
  int* cursor = (int*)wsb;       wsb += (size_t)Nn * sizeof(int);
  float* dinv = (float*)wsb;     wsb += (size_t)Nn * sizeof(float);
  size_t need = (size_t)(wsb - (char*)d_ws);
  if (need > ws_size) {
    fprintf(stderr, "kernel_launch: ws too small: need %zu have %zu\n", need, ws_size);
  }

  dim3 blk(256);

  // merged preprocessing: all casts + out=bias + counts=1
  int prep_total = Nn * K1 + N1PAD * K1 + NPAD * KPAD + N2PAD * K2PAD + 128 * N2PAD
                 + NGRAPH * 128 + Nn;
  prep_k<<<(prep_total + 255) / 256, 256, 0, stream>>>(x, Wl, Wr, W_gcn, W_fc1, W_fc2, b_fc2,
                                                       xbf, Wlrb, Wtb, Wfc1b, Wfc2b,
                                                       out, counts, Nn);

  // CSR by dst (self-loop slot first)
  count_k<<<512, 256, 0, stream>>>(dstv, E, counts);
  scan_k<<<1, 256, 0, stream>>>(counts, row_start, Nn);
  node_init_k<<<(Nn + 255) / 256, 256, 0, stream>>>(row_start, cursor, csr_src, dinv, Nn);
  scatter_k<<<512, 256, 0, stream>>>(srcv, dstv, E, cursor, csr_src);

  // transform GEMM (bf16 MFMA, BK=64): xbf @ Wlrb^T -> xl (bufBF) | xr (xrb), both bf16
  dim3 g1grid(N1PAD / 128, Nn / 128);
  gemm_bf16_dual_k<<<g1grid, blk, 0, stream>>>((const unsigned short*)xbf,
                                               (const unsigned short*)Wlrb,
                                               bufBF, xrb, Nn, N1, K1, K1);

  // GATv2 fused single-pass -> h1bf (bf16, KPAD stride, padded cols zeroed)
  gatv2_fused_k<<<Nn, 320, 0, stream>>>(bufBF, xrb, att, b_gat, row_start, csr_src, h1bf);

  // GCN matmul (bf16 MFMA, BK=64): h1bf @ Wtb^T -> h2 bf16 (bufBF, xl dead)
  dim3 g2grid(NPAD / 128, Nn / 128);
  gemm_bf16_obf_k<<<g2grid, blk, 0, stream>>>((const unsigned short*)h1bf,
                                              (const unsigned short*)Wtb,
                                              bufBF, Nn, F, KPAD, KPAD);

  // normalized aggregation (bf16 gather) -> bf16 aggbf (aliases dead xr)
  gcn_agg_k<<<Nn, 320, 0, stream>>>(bufBF, b_gcn, row_start, csr_src, dinv, aggbf);

  // pooling (bf16 in) -> bf16 pooled [NGRAPH x K2PAD], zero-padded
  pool_k<<<NGRAPH, 320, 0, stream>>>(aggbf, batch, pooledb, Nn);

  // FC1 (bf16 MFMA, BK=64): g1b = relu(pooled @ Wfc1b^T + b_fc1), bf16, padded to N2PAD
  dim3 fc1grid(N2PAD / 128, NGRAPH / 128);
  gemm_bf16_fc1_k<<<fc1grid, blk, 0, stream>>>((const unsigned short*)pooledb,
                                               (const unsigned short*)Wfc1b,
                                               b_fc1, g1b, NGRAPH, 1500, K2PAD, K2PAD);

  // FC2 (bf16 MFMA split-K): out += g1b @ Wfc2b^T (out pre-inited with b_fc2)
  dim3 fc2grid(1, NGRAPH / 128, 6);   // kchunk 256 -> 4 BK iters per block
  gemm_bf16_fc2_k<<<fc2grid, blk, 0, stream>>>((const unsigned short*)g1b,
                                               (const unsigned short*)Wfc2b,
                                               out, NGRAPH, 256);
}